// Round 8
// baseline (3316.733 us; speedup 1.0000x reference)
//
#include <hip/hip_runtime.h>
#include <cstdint>
#include <cstddef>

constexpr int NB  = 2;
constexpr int CO  = 64;
constexpr int DIM = 64;
constexpr int SP  = DIM * DIM * DIM;       // 262144
constexpr int NC  = NB * CO;               // 128
constexpr int Y_SZ = NB * CO * 32 * 32 * 32;

typedef float f32x4 __attribute__((ext_vector_type(4)));
typedef short s16x8 __attribute__((ext_vector_type(8)));

__device__ __forceinline__ unsigned short f2bf(float f) {
    unsigned int u = __float_as_uint(f);
    unsigned int r = (u + 0x7fffu + ((u >> 16) & 1u)) >> 16;
    return (unsigned short)r;
}
__device__ __forceinline__ float bf2f(unsigned short u) {
    return __uint_as_float((unsigned int)u << 16);
}
__device__ __forceinline__ unsigned int pack2(float a, float b) {
    return (unsigned int)f2bf(a) | ((unsigned int)f2bf(b) << 16);
}
// mish(x) = x * tanh(softplus(x)) = x*(e^2+2e)/(e^2+2e+2), e = exp(x)
__device__ __forceinline__ float mish_f(float x) {
    float e = __expf(x);
    float num = e * (e + 2.f);
    float r = x * num * __builtin_amdgcn_rcpf(num + 2.f);
    return (x > 15.f) ? x : r;
}

__device__ __forceinline__ void gload_lds16(const void* g, void* l) {
    __builtin_amdgcn_global_load_lds(
        (const __attribute__((address_space(1))) unsigned int*)g,
        (__attribute__((address_space(3))) unsigned int*)l, 16, 0, 0);
}

// -------------------------------------------------------- gate (+zero) ----
__global__ void gate_kernel(const float* __restrict__ t, const float* __restrict__ gw,
                            const float* __restrict__ gb, float* __restrict__ g,
                            float* __restrict__ zbuf) {
    int tid = threadIdx.x;
    if (tid >= 128) { if (tid < 192) zbuf[tid - 128] = 0.f; return; }
    int n = tid >> 6, co = tid & 63;
    float tl[10];
#pragma unroll
    for (int k = 0; k < 10; ++k) tl[k] = t[n * 10 + k];
    float l[5];
#pragma unroll
    for (int e = 0; e < 5; ++e) {
        int row = e * CO + co;
        float acc = gb[row];
#pragma unroll
        for (int k = 0; k < 10; ++k) acc += tl[k] * gw[row * 10 + k];
        l[e] = acc;
    }
    float m = l[0];
#pragma unroll
    for (int e = 1; e < 5; ++e) m = fmaxf(m, l[e]);
    float s = 0.f;
#pragma unroll
    for (int e = 0; e < 5; ++e) { l[e] = expf(l[e] - m); s += l[e]; }
    float inv = 1.f / s;
#pragma unroll
    for (int e = 0; e < 5; ++e) g[(n * 5 + e) * CO + co] = l[e] * inv;
}

// --------------------------------------------------------------- synth ----
// wbuf (bf16): [n][dz(5)][cich(CI/32)][t(25)][co(64)][cil(32)]
template <int CI>
__global__ void synth_kernel(const float* __restrict__ g,
                             const float* __restrict__ c5, const float* __restrict__ c3,
                             const float* __restrict__ c1, const float* __restrict__ a3,
                             const float* __restrict__ a5, unsigned short* __restrict__ wbuf) {
    int idx = blockIdx.x * 256 + threadIdx.x;
    constexpr int TOTAL = NB * CO * CI * 125;
    if (idx >= TOTAL) return;
    int tap = idx % 125;
    int ci  = (idx / 125) % CI;
    int co  = (idx / (125 * CI)) % CO;
    int n   = idx / (125 * CI * CO);
    const float* gn = g + n * 5 * CO;
    float g0 = gn[0 * CO + co], g1 = gn[1 * CO + co], g2 = gn[2 * CO + co],
          g3 = gn[3 * CO + co], g4 = gn[4 * CO + co];
    int dz = tap / 25, dy = (tap / 5) % 5, dx = tap % 5;
    int oc = co * CI + ci;
    float v = g0 * c5[(size_t)oc * 125 + tap] + g4 * a5[oc] * (1.f / 125.f);
    if (dz >= 1 && dz <= 3 && dy >= 1 && dy <= 3 && dx >= 1 && dx <= 3)
        v += g1 * c3[(size_t)oc * 27 + (dz - 1) * 9 + (dy - 1) * 3 + (dx - 1)]
           + g3 * a3[oc] * (1.f / 27.f);
    if (dz == 2 && dy == 2 && dx == 2) v += g2 * c1[oc];
    int t = (dy * 5 + dx);
    int cich = ci >> 5, cil = ci & 31;
    wbuf[((((size_t)(n * 5 + dz) * (CI / 32) + cich) * 25 + t) * 64 + co) * 32 + cil] = f2bf(v);
}

// -------------------------------------------------------------- x->CL -----
__global__ __launch_bounds__(256) void x_to_cl(const float* __restrict__ x,
                                               unsigned short* __restrict__ xcl) {
    __shared__ float ld[32][256];
    int b = blockIdx.x;                   // 2048 = n(2) x 1024
    int n = b >> 10;
    size_t base = (size_t)(b & 1023) * 256;
    int tid = threadIdx.x;
    const float* xp = x + (size_t)n * 32 * SP + base + tid;
#pragma unroll
    for (int c = 0; c < 32; ++c) ld[c][tid] = xp[(size_t)c * SP];
    __syncthreads();
    uint4* op = (uint4*)(xcl + ((size_t)n * SP + base) * 32);
#pragma unroll
    for (int r = 0; r < 4; ++r) {
        int idx = r * 256 + tid;
        int px = idx >> 2, q = idx & 3;
        uint4 o;
        o.x = pack2(ld[q * 8 + 0][px], ld[q * 8 + 1][px]);
        o.y = pack2(ld[q * 8 + 2][px], ld[q * 8 + 3][px]);
        o.z = pack2(ld[q * 8 + 4][px], ld[q * 8 + 5][px]);
        o.w = pack2(ld[q * 8 + 6][px], ld[q * 8 + 7][px]);
        op[idx] = o;
    }
}

// ----------------------------------------------------------- MFMA conv ----
// Input bf16 channel-last [n][zyx][CI]. Block (512 thr): (n, z-pair, yt, xt)
// -> 64co x 2z x 16y x 16x. Wave (yh 0..1, cq 0..3): 8 y-rows x 16 co for
// BOTH z-slices (staged planes + fr reads shared). Linear LDS staging via
// global_load_lds. Stats partials -> part[n][s][co][512].
template <int CI, bool OUT_CL>
__global__ __launch_bounds__(512, 4) void conv5_mfma(const unsigned short* __restrict__ xin,
                                                     const unsigned short* __restrict__ wbuf,
                                                     void* __restrict__ outp,
                                                     float* __restrict__ part,
                                                     const void* __restrict__ zbuf) {
    constexpr int NCH  = CI / 32;
    constexpr int NSTG = 6 * NCH;          // 6 planes x cich
    __shared__ __align__(16) unsigned short lds[2][12800];   // 2 x 25.6 KB

    const int b   = blockIdx.x;            // 1024 = n(2) x zp(32) x yt(4) x xt(4)
    const int xt  = b & 3;
    const int yt  = (b >> 2) & 3;
    const int zp  = (b >> 4) & 31;
    const int n   = b >> 9;
    const int z0  = zp * 2;
    const int tid = threadIdx.x;
    const int lane = tid & 63, wv = tid >> 6;
    const int xl = lane & 15, kh = lane >> 4;
    const int yh = wv >> 2, cq = wv & 3;

    f32x4 acc[2][8];
#pragma unroll
    for (int sl = 0; sl < 2; ++sl)
#pragma unroll
        for (int pt = 0; pt < 8; ++pt)
#pragma unroll
            for (int j = 0; j < 4; ++j) acc[sl][pt][j] = 0.f;

    // staging geometry: LDS slot idx = tid + r*512 (linear dest, 16B each)
    long goff[4]; int gval[4];
#pragma unroll
    for (int r = 0; r < 4; ++r) {
        int idx = tid + r * 512;
        int p = idx >> 2, khs = idx & 3;
        int xx = p % 20, yy = p / 20;
        int yi = yt * 16 - 2 + yy, xi = xt * 16 - 2 + xx;
        gval[r] = ((unsigned)yi < 64u) && ((unsigned)xi < 64u);
        goff[r] = ((long)(yi * 64 + xi) * CI + khs * 8) * 2;
    }

    auto stage = [&](int s, int buf) {
        int pp = s / NCH, cich = s % NCH;
        int zi = z0 - 2 + pp;
        bool zok = (unsigned)zi < 64u;
        const char* pb = (const char*)xin
                       + ((size_t)(n * SP + zi * 4096) * CI + cich * 32) * 2;
        char* lb = (char*)&lds[buf][0];
#pragma unroll
        for (int r = 0; r < 4; ++r) {
            int idx = tid + r * 512;
            if (idx < 1600) {
                const void* g = (zok && gval[r]) ? (const void*)(pb + goff[r]) : zbuf;
                gload_lds16(g, lb + idx * 16);
            }
        }
    };

    auto comp = [&](int s, int buf) {
        int pp = s / NCH, cich = s % NCH;
        const bool d0 = pp < 5;            // slice0 uses dz = pp
        const bool d1 = pp >= 1;           // slice1 uses dz = pp-1
        const unsigned short* wp0 = wbuf
            + ((size_t)((n * 5 + pp) * NCH + cich) * 25) * 2048
            + cq * 512 + xl * 32 + kh * 8;
        const unsigned short* wp1 = wbuf
            + ((size_t)((n * 5 + (pp - 1)) * NCH + cich) * 25) * 2048
            + cq * 512 + xl * 32 + kh * 8;
        const char* src = (const char*)&lds[buf][0];
        __builtin_amdgcn_s_setprio(1);
#pragma unroll 1
        for (int dx = 0; dx < 5; ++dx) {
            int xx = xl + dx;
            s16x8 fr[12];
#pragma unroll
            for (int r = 0; r < 12; ++r)
                fr[r] = *(const s16x8*)(src
                        + (size_t)((yh * 8 + r) * 20 + xx) * 64 + kh * 16);
            if (d0 && d1) {
#pragma unroll
                for (int dy = 0; dy < 5; ++dy) {
                    s16x8 a0 = *(const s16x8*)(wp0 + (size_t)(dy * 5 + dx) * 2048);
                    s16x8 a1 = *(const s16x8*)(wp1 + (size_t)(dy * 5 + dx) * 2048);
#pragma unroll
                    for (int pt = 0; pt < 8; ++pt) {
                        acc[0][pt] = __builtin_amdgcn_mfma_f32_16x16x32_bf16(
                            a0, fr[pt + dy], acc[0][pt], 0, 0, 0);
                        acc[1][pt] = __builtin_amdgcn_mfma_f32_16x16x32_bf16(
                            a1, fr[pt + dy], acc[1][pt], 0, 0, 0);
                    }
                }
            } else if (d0) {
#pragma unroll
                for (int dy = 0; dy < 5; ++dy) {
                    s16x8 a0 = *(const s16x8*)(wp0 + (size_t)(dy * 5 + dx) * 2048);
#pragma unroll
                    for (int pt = 0; pt < 8; ++pt)
                        acc[0][pt] = __builtin_amdgcn_mfma_f32_16x16x32_bf16(
                            a0, fr[pt + dy], acc[0][pt], 0, 0, 0);
                }
            } else {
#pragma unroll
                for (int dy = 0; dy < 5; ++dy) {
                    s16x8 a1 = *(const s16x8*)(wp1 + (size_t)(dy * 5 + dx) * 2048);
#pragma unroll
                    for (int pt = 0; pt < 8; ++pt)
                        acc[1][pt] = __builtin_amdgcn_mfma_f32_16x16x32_bf16(
                            a1, fr[pt + dy], acc[1][pt], 0, 0, 0);
                }
            }
        }
        __builtin_amdgcn_s_setprio(0);
    };

    stage(0, 0);
    __syncthreads();
#pragma unroll 1
    for (int s = 0; s < NSTG; ++s) {
        if (s + 1 < NSTG) stage(s + 1, (s + 1) & 1);
        comp(s, s & 1);
        __syncthreads();
    }

    // ---- fused instance-norm partials (both slices) ----
    float* sh1 = (float*)&lds[0][0];          // [2 yh][64 co]
    float* sh2 = sh1 + 128;
    {
        float s1[4], s2[4];
#pragma unroll
        for (int j = 0; j < 4; ++j) { s1[j] = 0.f; s2[j] = 0.f; }
#pragma unroll
        for (int sl = 0; sl < 2; ++sl)
#pragma unroll
            for (int pt = 0; pt < 8; ++pt)
#pragma unroll
                for (int j = 0; j < 4; ++j) {
                    float v = acc[sl][pt][j];
                    s1[j] += v; s2[j] += v * v;
                }
#pragma unroll
        for (int o = 1; o < 16; o <<= 1)
#pragma unroll
            for (int j = 0; j < 4; ++j) {
                s1[j] += __shfl_xor(s1[j], o, 64);
                s2[j] += __shfl_xor(s2[j], o, 64);
            }
        if (xl == 0) {
#pragma unroll
            for (int j = 0; j < 4; ++j) {
                int co = cq * 16 + kh * 4 + j;
                sh1[yh * 64 + co] = s1[j];
                sh2[yh * 64 + co] = s2[j];
            }
        }
    }

    char* tb = (char*)&lds[0][0] + 2048;      // 32 KB transpose buffer (CL)
    if (OUT_CL) {
#pragma unroll
        for (int pt = 0; pt < 8; ++pt) {
            int pix = (yh * 8 + pt) * 16 + xl;
            unsigned int ad = ((unsigned)(pix * 128 + cq * 32 + kh * 8))
                              ^ ((unsigned)(pix & 7) << 4);
            *(unsigned int*)(tb + ad)     = pack2(acc[0][pt][0], acc[0][pt][1]);
            *(unsigned int*)(tb + ad + 4) = pack2(acc[0][pt][2], acc[0][pt][3]);
        }
    }
    __syncthreads();

    if (tid < 128) {
        int co = tid & 63, si = tid >> 6;
        const float* shp = si ? sh2 : sh1;
        float v = shp[co] + shp[64 + co];
        part[((size_t)(n * 2 + si) * 64 + co) * 512 + (b & 511)] = v;
    }

    if (OUT_CL) {
        // slice 0 out
#pragma unroll
        for (int it = 0; it < 4; ++it) {
            int idx = it * 512 + tid;
            int pix = idx >> 3, ch = idx & 7;
            uint4 v = *(const uint4*)(tb + (((unsigned)idx * 16)
                                            ^ ((unsigned)(pix & 7) << 4)));
            int y = yt * 16 + (pix >> 4), x = xt * 16 + (pix & 15);
            *(uint4*)((unsigned short*)outp
                      + ((size_t)(n * SP + z0 * 4096 + y * 64 + x) * 64 + ch * 8)) = v;
        }
        __syncthreads();
#pragma unroll
        for (int pt = 0; pt < 8; ++pt) {
            int pix = (yh * 8 + pt) * 16 + xl;
            unsigned int ad = ((unsigned)(pix * 128 + cq * 32 + kh * 8))
                              ^ ((unsigned)(pix & 7) << 4);
            *(unsigned int*)(tb + ad)     = pack2(acc[1][pt][0], acc[1][pt][1]);
            *(unsigned int*)(tb + ad + 4) = pack2(acc[1][pt][2], acc[1][pt][3]);
        }
        __syncthreads();
#pragma unroll
        for (int it = 0; it < 4; ++it) {
            int idx = it * 512 + tid;
            int pix = idx >> 3, ch = idx & 7;
            uint4 v = *(const uint4*)(tb + (((unsigned)idx * 16)
                                            ^ ((unsigned)(pix & 7) << 4)));
            int y = yt * 16 + (pix >> 4), x = xt * 16 + (pix & 15);
            *(uint4*)((unsigned short*)outp
                      + ((size_t)(n * SP + (z0 + 1) * 4096 + y * 64 + x) * 64 + ch * 8)) = v;
        }
    } else {
        float* op = (float*)outp;
#pragma unroll
        for (int sl = 0; sl < 2; ++sl)
#pragma unroll
            for (int pt = 0; pt < 8; ++pt) {
                int y = yt * 16 + yh * 8 + pt;
#pragma unroll
                for (int j = 0; j < 4; ++j)
                    op[((size_t)(n * 64 + cq * 16 + kh * 4 + j) * 64 + (z0 + sl)) * 4096
                       + y * 64 + xt * 16 + xl] = acc[sl][pt][j];
            }
    }
}

// ------------------------------------------------- stats finalize ---------
// part: [n][s][co][CH] contiguous rows. grid = 128 (n*64+co), 256 thr.
template <int CH>
__global__ void stats_fin(const float* __restrict__ part, float* __restrict__ st,
                          float invS) {
    int blk = blockIdx.x;
    int n = blk >> 6, co = blk & 63;
    int tid = threadIdx.x;
    const float* ps = part + ((size_t)(n * 2 + 0) * 64 + co) * CH;
    const float* pq = part + ((size_t)(n * 2 + 1) * 64 + co) * CH;
    float s1 = 0.f, s2 = 0.f;
    for (int i = tid; i < CH; i += 256) { s1 += ps[i]; s2 += pq[i]; }
#pragma unroll
    for (int o = 1; o < 64; o <<= 1) {
        s1 += __shfl_xor(s1, o, 64);
        s2 += __shfl_xor(s2, o, 64);
    }
    __shared__ float sh1[4], sh2[4];
    if ((tid & 63) == 0) { sh1[tid >> 6] = s1; sh2[tid >> 6] = s2; }
    __syncthreads();
    if (tid == 0) {
        float a = sh1[0] + sh1[1] + sh1[2] + sh1[3];
        float q = sh2[0] + sh2[1] + sh2[2] + sh2[3];
        float mean = a * invS;
        float var  = q * invS - mean * mean;
        st[(n * 64 + co) * 2]     = mean;
        st[(n * 64 + co) * 2 + 1] = rsqrtf(var + 1e-5f);
    }
}

// -------------------------------------- norm+mish in-place, channel-last --
__global__ void norm_mish_cl_kernel(unsigned short* __restrict__ h,
                                    const float* __restrict__ st,
                                    const float* __restrict__ gamma,
                                    const float* __restrict__ beta) {
    size_t idx = (size_t)blockIdx.x * 256 + threadIdx.x;   // NB*SP*8 items
    uint4 v = ((uint4*)h)[idx];
    int c0 = ((int)(idx & 7)) * 8;
    size_t pix = idx >> 3;
    int n = (int)(pix >> 18);
    unsigned int* pv = &v.x;
#pragma unroll
    for (int q = 0; q < 4; ++q) {
        unsigned int wv = pv[q];
        unsigned int out = 0;
#pragma unroll
        for (int hv = 0; hv < 2; ++hv) {
            int c = c0 + 2 * q + hv;
            int nc = n * 64 + c;
            float val = bf2f((unsigned short)((wv >> (16 * hv)) & 0xffffu));
            float xh = (val - st[nc * 2]) * st[nc * 2 + 1] * gamma[c] + beta[c];
            out |= ((unsigned int)f2bf(mish_f(xh))) << (16 * hv);
        }
        pv[q] = out;
    }
    ((uint4*)h)[idx] = v;
}

// ----------------------------------------------------------- norm+mish ----
template <int SHIFT>
__global__ void norm_mish_kernel(float* __restrict__ buf, const float* __restrict__ stats,
                                 const float* __restrict__ gamma, const float* __restrict__ beta,
                                 int total4) {
    int idx = blockIdx.x * 256 + threadIdx.x;
    if (idx >= total4) return;
    float4 v = reinterpret_cast<float4*>(buf)[idx];
    int nc = idx >> (SHIFT - 2);
    int c  = nc & 63;
    float mean = stats[nc * 2], inv = stats[nc * 2 + 1];
    float ga = gamma[c], be = beta[c];
    float* pv = &v.x;
#pragma unroll
    for (int k = 0; k < 4; ++k) {
        float xh = (pv[k] - mean) * inv * ga + be;
        pv[k] = mish_f(xh);
    }
    reinterpret_cast<float4*>(buf)[idx] = v;
}

// ----------------------------------------------------------- down conv ----
// Fused: reads RAW xskip, applies norm+mish (st2), writes normalized back,
// 2x2x2 stride-2 conv, writes raw y + y-stats partials [n][s][co][256].
__global__ __launch_bounds__(256) void down_conv_kernel(float* __restrict__ xin,
                                                        const float* __restrict__ dw,
                                                        const float* __restrict__ st,
                                                        const float* __restrict__ gamma,
                                                        const float* __restrict__ beta,
                                                        float* __restrict__ out,
                                                        float* __restrict__ part) {
    __shared__ float ls[8][2][8][64];
    int b   = blockIdx.x;
    int yt  = b & 7;
    int z   = (b >> 3) & 31;
    int n   = b >> 8;
    int tid = threadIdx.x;
    int xo  = tid & 31;
    int cog = tid >> 5;

    float acc[4][8];
#pragma unroll
    for (int yo = 0; yo < 4; ++yo)
#pragma unroll
        for (int j = 0; j < 8; ++j) acc[yo][j] = 0.f;

    for (int cc = 0; cc < 8; ++cc) {
        for (int idx = tid; idx < 8192; idx += 256) {
            int xx = idx & 63;
            int yy = (idx >> 6) & 7;
            int dz = (idx >> 9) & 1;
            int c  = idx >> 10;
            int ci = cc * 8 + c;
            size_t ga = ((size_t)(n * CO + ci) * 64 + 2 * z + dz) * 4096
                      + (yt * 8 + yy) * 64 + xx;
            float v = xin[ga];
            int nc = n * 64 + ci;
            float nv = mish_f((v - st[nc * 2]) * st[nc * 2 + 1] * gamma[ci] + beta[ci]);
            ls[c][dz][yy][xx] = nv;
            xin[ga] = nv;
        }
        __syncthreads();
#pragma unroll 1
        for (int c = 0; c < 8; ++c) {
            int ci = cc * 8 + c;
#pragma unroll
            for (int tap = 0; tap < 8; ++tap) {
                int dz = tap >> 2, dy = (tap >> 1) & 1, dx = tap & 1;
                float w[8];
#pragma unroll
                for (int j = 0; j < 8; ++j)
                    w[j] = dw[((size_t)(cog * 8 + j) * CO + ci) * 8 + tap];
#pragma unroll
                for (int yo = 0; yo < 4; ++yo) {
                    float xv = ls[c][dz][yo * 2 + dy][2 * xo + dx];
#pragma unroll
                    for (int j = 0; j < 8; ++j) acc[yo][j] += w[j] * xv;
                }
            }
        }
        __syncthreads();
    }
#pragma unroll
    for (int yo = 0; yo < 4; ++yo)
#pragma unroll
        for (int j = 0; j < 8; ++j)
            out[((size_t)(n * CO + cog * 8 + j) * 32 + z) * 1024 + (yt * 4 + yo) * 32 + xo]
                = acc[yo][j];

    // y-stats partials
    float s1[8], s2[8];
#pragma unroll
    for (int j = 0; j < 8; ++j) { s1[j] = 0.f; s2[j] = 0.f; }
#pragma unroll
    for (int yo = 0; yo < 4; ++yo)
#pragma unroll
        for (int j = 0; j < 8; ++j) {
            float v = acc[yo][j];
            s1[j] += v; s2[j] += v * v;
        }
#pragma unroll
    for (int o = 1; o < 32; o <<= 1)
#pragma unroll
        for (int j = 0; j < 8; ++j) {
            s1[j] += __shfl_xor(s1[j], o, 64);
            s2[j] += __shfl_xor(s2[j], o, 64);
        }
    if (xo == 0) {
        int cb = b & 255;
#pragma unroll
        for (int j = 0; j < 8; ++j) {
            int co = cog * 8 + j;
            part[((size_t)(n * 2 + 0) * 64 + co) * 256 + cb] = s1[j];
            part[((size_t)(n * 2 + 1) * 64 + co) * 256 + cb] = s2[j];
        }
    }
}

// -------------------------------------------------------------- launch ----
extern "C" void kernel_launch(void* const* d_in, const int* in_sizes, int n_in,
                              void* d_out, int out_size, void* d_ws, size_t ws_size,
                              hipStream_t stream) {
    const float* x      = (const float*)d_in[0];
    const float* t      = (const float*)d_in[1];
    const float* l1_c5  = (const float*)d_in[2];
    const float* l1_c3  = (const float*)d_in[3];
    const float* l1_c1  = (const float*)d_in[4];
    const float* l1_a3  = (const float*)d_in[5];
    const float* l1_a5  = (const float*)d_in[6];
    const float* l1_gw  = (const float*)d_in[7];
    const float* l1_gb  = (const float*)d_in[8];
    const float* l1_ga  = (const float*)d_in[9];
    const float* l1_be  = (const float*)d_in[10];
    const float* l2_c5  = (const float*)d_in[11];
    const float* l2_c3  = (const float*)d_in[12];
    const float* l2_c1  = (const float*)d_in[13];
    const float* l2_a3  = (const float*)d_in[14];
    const float* l2_a5  = (const float*)d_in[15];
    const float* l2_gw  = (const float*)d_in[16];
    const float* l2_gb  = (const float*)d_in[17];
    const float* l2_ga  = (const float*)d_in[18];
    const float* l2_be  = (const float*)d_in[19];
    const float* down_w = (const float*)d_in[20];
    const float* dn_ga  = (const float*)d_in[21];
    const float* dn_be  = (const float*)d_in[22];

    char* ws = (char*)d_ws;
    unsigned short* xcl = (unsigned short*)(ws);                  // 33,554,432 B
    unsigned short* h2  = (unsigned short*)(ws + 33554432);       // 67,108,864 B
    unsigned short* w1  = (unsigned short*)(ws + 100663296);      //  1,024,000 B
    unsigned short* w2  = (unsigned short*)(ws + 101687296);      //  2,048,000 B
    float* g1    = (float*)(ws + 103735296);
    float* g2    = (float*)(ws + 103737856);
    float* st1   = (float*)(ws + 103740416);
    float* st2   = (float*)(ws + 103741440);
    float* st3   = (float*)(ws + 103742464);
    float* part1 = (float*)(ws + 103743488);                      //    524,288 B
    float* part2 = (float*)(ws + 104267776);                      //    524,288 B
    float* part3 = (float*)(ws + 104792064);                      //    262,144 B
    float* zbuf  = (float*)(ws + 105054208);                      //        256 B

    float* yout  = (float*)d_out;
    float* xskip = (float*)d_out + Y_SZ;

    gate_kernel<<<1, 192, 0, stream>>>(t, l1_gw, l1_gb, g1, zbuf);
    gate_kernel<<<1, 192, 0, stream>>>(t, l2_gw, l2_gb, g2, zbuf);
    synth_kernel<32><<<(NB * CO * 32 * 125 + 255) / 256, 256, 0, stream>>>(
        g1, l1_c5, l1_c3, l1_c1, l1_a3, l1_a5, w1);
    synth_kernel<64><<<(NB * CO * 64 * 125 + 255) / 256, 256, 0, stream>>>(
        g2, l2_c5, l2_c3, l2_c1, l2_a3, l2_a5, w2);
    x_to_cl<<<2048, 256, 0, stream>>>(x, xcl);

    // layer 1: conv (bf16 CL in -> bf16 CL raw out) + fused stats partials
    conv5_mfma<32, true><<<1024, 512, 0, stream>>>(xcl, w1, h2, part1, zbuf);
    stats_fin<512><<<128, 256, 0, stream>>>(part1, st1, 1.f / SP);
    norm_mish_cl_kernel<<<16384, 256, 0, stream>>>(h2, st1, l1_ga, l1_be);

    // layer 2: conv (bf16 CL in -> f32 NCDHW raw into x_skip) + partials
    conv5_mfma<64, false><<<1024, 512, 0, stream>>>(h2, w2, xskip, part2, zbuf);
    stats_fin<512><<<128, 256, 0, stream>>>(part2, st2, 1.f / SP);

    // downsample: fused norm+mish(x_skip, in place) + conv + y-stats partials
    down_conv_kernel<<<NB * 32 * 8, 256, 0, stream>>>(xskip, down_w, st2, l2_ga, l2_be,
                                                      yout, part3);
    stats_fin<256><<<128, 256, 0, stream>>>(part3, st3, 1.f / 32768.f);
    norm_mish_kernel<15><<<(NC * 32768 / 4 + 255) / 256, 256, 0, stream>>>(
        yout, st3, dn_ga, dn_be, NC * 32768 / 4);
}

// Round 10
// 851.483 us; speedup vs baseline: 3.8952x; 3.8952x over previous
//
#include <hip/hip_runtime.h>
#include <cstdint>
#include <cstddef>

constexpr int NB  = 2;
constexpr int CO  = 64;
constexpr int DIM = 64;
constexpr int SP  = DIM * DIM * DIM;       // 262144
constexpr int NC  = NB * CO;               // 128
constexpr int Y_SZ = NB * CO * 32 * 32 * 32;

typedef float f32x4 __attribute__((ext_vector_type(4)));
typedef short s16x8 __attribute__((ext_vector_type(8)));

__device__ __forceinline__ unsigned short f2bf(float f) {
    unsigned int u = __float_as_uint(f);
    unsigned int r = (u + 0x7fffu + ((u >> 16) & 1u)) >> 16;
    return (unsigned short)r;
}
__device__ __forceinline__ float bf2f(unsigned short u) {
    return __uint_as_float((unsigned int)u << 16);
}
__device__ __forceinline__ unsigned int pack2(float a, float b) {
    return (unsigned int)f2bf(a) | ((unsigned int)f2bf(b) << 16);
}
// mish(x) = x * tanh(softplus(x)) = x*(e^2+2e)/(e^2+2e+2), e = exp(x)
__device__ __forceinline__ float mish_f(float x) {
    float e = __expf(x);
    float num = e * (e + 2.f);
    float r = x * num * __builtin_amdgcn_rcpf(num + 2.f);
    return (x > 15.f) ? x : r;
}

__device__ __forceinline__ void gload_lds16(const void* g, void* l) {
    __builtin_amdgcn_global_load_lds(
        (const __attribute__((address_space(1))) unsigned int*)g,
        (__attribute__((address_space(3))) unsigned int*)l, 16, 0, 0);
}

// -------------------------------------------------------- gate (+zero) ----
__global__ void gate_kernel(const float* __restrict__ t, const float* __restrict__ gw,
                            const float* __restrict__ gb, float* __restrict__ g,
                            float* __restrict__ zbuf) {
    int tid = threadIdx.x;
    if (tid >= 128) { if (tid < 192) zbuf[tid - 128] = 0.f; return; }
    int n = tid >> 6, co = tid & 63;
    float tl[10];
#pragma unroll
    for (int k = 0; k < 10; ++k) tl[k] = t[n * 10 + k];
    float l[5];
#pragma unroll
    for (int e = 0; e < 5; ++e) {
        int row = e * CO + co;
        float acc = gb[row];
#pragma unroll
        for (int k = 0; k < 10; ++k) acc += tl[k] * gw[row * 10 + k];
        l[e] = acc;
    }
    float m = l[0];
#pragma unroll
    for (int e = 1; e < 5; ++e) m = fmaxf(m, l[e]);
    float s = 0.f;
#pragma unroll
    for (int e = 0; e < 5; ++e) { l[e] = expf(l[e] - m); s += l[e]; }
    float inv = 1.f / s;
#pragma unroll
    for (int e = 0; e < 5; ++e) g[(n * 5 + e) * CO + co] = l[e] * inv;
}

// --------------------------------------------------------------- synth ----
// wbuf (bf16): [n][dz(5)][cich(CI/32)][t(25)][co(64)][cil(32)]
template <int CI>
__global__ void synth_kernel(const float* __restrict__ g,
                             const float* __restrict__ c5, const float* __restrict__ c3,
                             const float* __restrict__ c1, const float* __restrict__ a3,
                             const float* __restrict__ a5, unsigned short* __restrict__ wbuf) {
    int idx = blockIdx.x * 256 + threadIdx.x;
    constexpr int TOTAL = NB * CO * CI * 125;
    if (idx >= TOTAL) return;
    int tap = idx % 125;
    int ci  = (idx / 125) % CI;
    int co  = (idx / (125 * CI)) % CO;
    int n   = idx / (125 * CI * CO);
    const float* gn = g + n * 5 * CO;
    float g0 = gn[0 * CO + co], g1 = gn[1 * CO + co], g2 = gn[2 * CO + co],
          g3 = gn[3 * CO + co], g4 = gn[4 * CO + co];
    int dz = tap / 25, dy = (tap / 5) % 5, dx = tap % 5;
    int oc = co * CI + ci;
    float v = g0 * c5[(size_t)oc * 125 + tap] + g4 * a5[oc] * (1.f / 125.f);
    if (dz >= 1 && dz <= 3 && dy >= 1 && dy <= 3 && dx >= 1 && dx <= 3)
        v += g1 * c3[(size_t)oc * 27 + (dz - 1) * 9 + (dy - 1) * 3 + (dx - 1)]
           + g3 * a3[oc] * (1.f / 27.f);
    if (dz == 2 && dy == 2 && dx == 2) v += g2 * c1[oc];
    int t = (dy * 5 + dx);
    int cich = ci >> 5, cil = ci & 31;
    wbuf[((((size_t)(n * 5 + dz) * (CI / 32) + cich) * 25 + t) * 64 + co) * 32 + cil] = f2bf(v);
}

// -------------------------------------------------------------- x->CL -----
__global__ __launch_bounds__(256) void x_to_cl(const float* __restrict__ x,
                                               unsigned short* __restrict__ xcl) {
    __shared__ float ld[32][256];
    int b = blockIdx.x;                   // 2048 = n(2) x 1024
    int n = b >> 10;
    size_t base = (size_t)(b & 1023) * 256;
    int tid = threadIdx.x;
    const float* xp = x + (size_t)n * 32 * SP + base + tid;
#pragma unroll
    for (int c = 0; c < 32; ++c) ld[c][tid] = xp[(size_t)c * SP];
    __syncthreads();
    uint4* op = (uint4*)(xcl + ((size_t)n * SP + base) * 32);
#pragma unroll
    for (int r = 0; r < 4; ++r) {
        int idx = r * 256 + tid;
        int px = idx >> 2, q = idx & 3;
        uint4 o;
        o.x = pack2(ld[q * 8 + 0][px], ld[q * 8 + 1][px]);
        o.y = pack2(ld[q * 8 + 2][px], ld[q * 8 + 3][px]);
        o.z = pack2(ld[q * 8 + 4][px], ld[q * 8 + 5][px]);
        o.w = pack2(ld[q * 8 + 6][px], ld[q * 8 + 7][px]);
        op[idx] = o;
    }
}

// ----------------------------------------------------------- MFMA conv ----
// Input bf16 channel-last [n][zyx][CI]. Block (512 thr): (n,z,yt,xt) ->
// 64co x 16y x 16x. Wave (yh 0..1, cq 0..3): 8 y-rows x 16 co. Linear LDS
// staging via global_load_lds (no swizzle — SQ_LDS_BANK_CONFLICT is a fixed
// 4-per-b128 artifact, measured R2..R7). Stats partials -> part[n][s][co][2048].
template <int CI, bool OUT_CL, int PCH>
__global__ __launch_bounds__(512, 4) void conv5_mfma(const unsigned short* __restrict__ xin,
                                                     const unsigned short* __restrict__ wbuf,
                                                     void* __restrict__ outp,
                                                     float* __restrict__ part,
                                                     const void* __restrict__ zbuf) {
    constexpr int NCH = CI / 32;
    constexpr int NS  = 5 * NCH;
    __shared__ __align__(16) unsigned short lds[2][12800];   // 2 x 25.6 KB

    const int b   = blockIdx.x;
    const int xt  = b & 3;
    const int yt  = (b >> 2) & 3;
    const int z   = (b >> 4) & 63;
    const int n   = b >> 10;
    const int tid = threadIdx.x;
    const int lane = tid & 63, wv = tid >> 6;
    const int xl = lane & 15, kh = lane >> 4;
    const int yh = wv >> 2, cq = wv & 3;

    f32x4 acc[8];
#pragma unroll
    for (int pt = 0; pt < 8; ++pt)
#pragma unroll
        for (int j = 0; j < 4; ++j) acc[pt][j] = 0.f;

    // staging geometry: LDS slot idx = tid + r*512 (linear dest, 16B each)
    long goff[4]; int gval[4];
#pragma unroll
    for (int r = 0; r < 4; ++r) {
        int idx = tid + r * 512;
        int p = idx >> 2, khs = idx & 3;
        int xx = p % 20, yy = p / 20;
        int yi = yt * 16 - 2 + yy, xi = xt * 16 - 2 + xx;
        gval[r] = ((unsigned)yi < 64u) && ((unsigned)xi < 64u);
        goff[r] = ((long)(yi * 64 + xi) * CI + khs * 8) * 2;
    }

    auto stage = [&](int s, int buf) {
        int dz = s / NCH, cich = s % NCH;
        int zi = z + dz - 2;
        bool zok = (unsigned)zi < 64u;
        const char* pb = (const char*)xin
                       + ((size_t)(n * SP + zi * 4096) * CI + cich * 32) * 2;
        char* lb = (char*)&lds[buf][0];
#pragma unroll
        for (int r = 0; r < 4; ++r) {
            int idx = tid + r * 512;
            if (idx < 1600) {
                const void* g = (zok && gval[r]) ? (const void*)(pb + goff[r]) : zbuf;
                gload_lds16(g, lb + idx * 16);
            }
        }
    };

    auto compute = [&](int s, int buf) {
        int dz = s / NCH, cich = s % NCH;
        const unsigned short* wp = wbuf
            + ((size_t)((n * 5 + dz) * NCH + cich) * 25) * 2048
            + cq * 512 + xl * 32 + kh * 8;
        const char* src = (const char*)&lds[buf][0];
        __builtin_amdgcn_s_setprio(1);
#pragma unroll 1
        for (int dx = 0; dx < 5; ++dx) {
            int xx = xl + dx;
            s16x8 fr[12];
#pragma unroll
            for (int r = 0; r < 12; ++r) {
                int row = yh * 8 + r;
                fr[r] = *(const s16x8*)(src + (size_t)(row * 20 + xx) * 64 + kh * 16);
            }
#pragma unroll
            for (int dy = 0; dy < 5; ++dy) {
                s16x8 a = *(const s16x8*)(wp + (size_t)(dy * 5 + dx) * 2048);
#pragma unroll
                for (int pt = 0; pt < 8; ++pt)
                    acc[pt] = __builtin_amdgcn_mfma_f32_16x16x32_bf16(
                        a, fr[pt + dy], acc[pt], 0, 0, 0);
            }
        }
        __builtin_amdgcn_s_setprio(0);
    };

    stage(0, 0);
    __syncthreads();
#pragma unroll 1
    for (int s = 0; s < NS; ++s) {
        if (s + 1 < NS) stage(s + 1, (s + 1) & 1);
        compute(s, s & 1);
        __syncthreads();
    }

    // ---- fused instance-norm partial sums -> part[n][s][co][PCH] ----
    {
        float s1[4], s2[4];
#pragma unroll
        for (int j = 0; j < 4; ++j) { s1[j] = 0.f; s2[j] = 0.f; }
#pragma unroll
        for (int pt = 0; pt < 8; ++pt)
#pragma unroll
            for (int j = 0; j < 4; ++j) {
                float v = acc[pt][j];
                s1[j] += v; s2[j] += v * v;
            }
#pragma unroll
        for (int o = 1; o < 16; o <<= 1)
#pragma unroll
            for (int j = 0; j < 4; ++j) {
                s1[j] += __shfl_xor(s1[j], o, 64);
                s2[j] += __shfl_xor(s2[j], o, 64);
            }
        if (xl == 0) {
            int co = cq * 16 + kh * 4;
            int cb = (b & 1023) * 2 + yh;
#pragma unroll
            for (int j = 0; j < 4; ++j) {
                part[((size_t)(n * 2 + 0) * 64 + co + j) * PCH + cb] = s1[j];
                part[((size_t)(n * 2 + 1) * 64 + co + j) * PCH + cb] = s2[j];
            }
        }
    }

    if (OUT_CL) {
        // transpose via XOR-swizzled LDS [pix(256)][co(64)] bf16 -> coalesced
        char* tb = (char*)&lds[0][0];     // 32 KB
#pragma unroll
        for (int pt = 0; pt < 8; ++pt) {
            int pix = (yh * 8 + pt) * 16 + xl;
            unsigned int ad = ((unsigned)(pix * 128 + cq * 32 + kh * 8))
                              ^ ((unsigned)(pix & 7) << 4);
            *(unsigned int*)(tb + ad)     = pack2(acc[pt][0], acc[pt][1]);
            *(unsigned int*)(tb + ad + 4) = pack2(acc[pt][2], acc[pt][3]);
        }
        __syncthreads();
#pragma unroll
        for (int it = 0; it < 4; ++it) {
            int idx = it * 512 + tid;
            int pix = idx >> 3, ch = idx & 7;
            uint4 v = *(const uint4*)(tb + (((unsigned)idx * 16)
                                            ^ ((unsigned)(pix & 7) << 4)));
            int y = yt * 16 + (pix >> 4), x = xt * 16 + (pix & 15);
            *(uint4*)((unsigned short*)outp
                      + ((size_t)(n * SP + z * 4096 + y * 64 + x) * 64 + ch * 8)) = v;
        }
    } else {
        float* op = (float*)outp;
#pragma unroll
        for (int pt = 0; pt < 8; ++pt) {
            int y = yt * 16 + yh * 8 + pt;
#pragma unroll
            for (int j = 0; j < 4; ++j)
                op[((size_t)(n * 64 + cq * 16 + kh * 4 + j) * 64 + z) * 4096
                   + y * 64 + xt * 16 + xl] = acc[pt][j];
        }
    }
}

// ------------------------------------------------- stats finalize ---------
// part: [n][s][co][CH] contiguous rows. grid = 128 (n*64+co), 256 thr.
template <int CH>
__global__ void stats_fin(const float* __restrict__ part, float* __restrict__ st,
                          float invS) {
    int blk = blockIdx.x;
    int n = blk >> 6, co = blk & 63;
    int tid = threadIdx.x;
    const float* ps = part + ((size_t)(n * 2 + 0) * 64 + co) * CH;
    const float* pq = part + ((size_t)(n * 2 + 1) * 64 + co) * CH;
    float s1 = 0.f, s2 = 0.f;
    for (int i = tid; i < CH; i += 256) { s1 += ps[i]; s2 += pq[i]; }
#pragma unroll
    for (int o = 1; o < 64; o <<= 1) {
        s1 += __shfl_xor(s1, o, 64);
        s2 += __shfl_xor(s2, o, 64);
    }
    __shared__ float sh1[4], sh2[4];
    if ((tid & 63) == 0) { sh1[tid >> 6] = s1; sh2[tid >> 6] = s2; }
    __syncthreads();
    if (tid == 0) {
        float a = sh1[0] + sh1[1] + sh1[2] + sh1[3];
        float q = sh2[0] + sh2[1] + sh2[2] + sh2[3];
        float mean = a * invS;
        float var  = q * invS - mean * mean;
        st[(n * 64 + co) * 2]     = mean;
        st[(n * 64 + co) * 2 + 1] = rsqrtf(var + 1e-5f);
    }
}

// -------------------------------------- norm+mish in-place, channel-last --
__global__ void norm_mish_cl_kernel(unsigned short* __restrict__ h,
                                    const float* __restrict__ st,
                                    const float* __restrict__ gamma,
                                    const float* __restrict__ beta) {
    size_t idx = (size_t)blockIdx.x * 256 + threadIdx.x;   // NB*SP*8 items
    uint4 v = ((uint4*)h)[idx];
    int c0 = ((int)(idx & 7)) * 8;
    size_t pix = idx >> 3;
    int n = (int)(pix >> 18);
    unsigned int* pv = &v.x;
#pragma unroll
    for (int q = 0; q < 4; ++q) {
        unsigned int wv = pv[q];
        unsigned int out = 0;
#pragma unroll
        for (int hv = 0; hv < 2; ++hv) {
            int c = c0 + 2 * q + hv;
            int nc = n * 64 + c;
            float val = bf2f((unsigned short)((wv >> (16 * hv)) & 0xffffu));
            float xh = (val - st[nc * 2]) * st[nc * 2 + 1] * gamma[c] + beta[c];
            out |= ((unsigned int)f2bf(mish_f(xh))) << (16 * hv);
        }
        pv[q] = out;
    }
    ((uint4*)h)[idx] = v;
}

// ----------------------------------------------------------- norm+mish ----
template <int SHIFT>
__global__ void norm_mish_kernel(float* __restrict__ buf, const float* __restrict__ stats,
                                 const float* __restrict__ gamma, const float* __restrict__ beta,
                                 int total4) {
    int idx = blockIdx.x * 256 + threadIdx.x;
    if (idx >= total4) return;
    float4 v = reinterpret_cast<float4*>(buf)[idx];
    int nc = idx >> (SHIFT - 2);
    int c  = nc & 63;
    float mean = stats[nc * 2], inv = stats[nc * 2 + 1];
    float ga = gamma[c], be = beta[c];
    float* pv = &v.x;
#pragma unroll
    for (int k = 0; k < 4; ++k) {
        float xh = (pv[k] - mean) * inv * ga + be;
        pv[k] = mish_f(xh);
    }
    reinterpret_cast<float4*>(buf)[idx] = v;
}

// ----------------------------------------------------------- down conv ----
// Fused: reads RAW xskip, applies norm+mish (st2), writes normalized back,
// 2x2x2 stride-2 conv, writes raw y + y-stats partials [n][s][co][256].
__global__ __launch_bounds__(256) void down_conv_kernel(float* __restrict__ xin,
                                                        const float* __restrict__ dw,
                                                        const float* __restrict__ st,
                                                        const float* __restrict__ gamma,
                                                        const float* __restrict__ beta,
                                                        float* __restrict__ out,
                                                        float* __restrict__ part) {
    __shared__ float ls[8][2][8][64];
    int b   = blockIdx.x;
    int yt  = b & 7;
    int z   = (b >> 3) & 31;
    int n   = b >> 8;
    int tid = threadIdx.x;
    int xo  = tid & 31;
    int cog = tid >> 5;

    float acc[4][8];
#pragma unroll
    for (int yo = 0; yo < 4; ++yo)
#pragma unroll
        for (int j = 0; j < 8; ++j) acc[yo][j] = 0.f;

    for (int cc = 0; cc < 8; ++cc) {
        for (int idx = tid; idx < 8192; idx += 256) {
            int xx = idx & 63;
            int yy = (idx >> 6) & 7;
            int dz = (idx >> 9) & 1;
            int c  = idx >> 10;
            int ci = cc * 8 + c;
            size_t ga = ((size_t)(n * CO + ci) * 64 + 2 * z + dz) * 4096
                      + (yt * 8 + yy) * 64 + xx;
            float v = xin[ga];
            int nc = n * 64 + ci;
            float nv = mish_f((v - st[nc * 2]) * st[nc * 2 + 1] * gamma[ci] + beta[ci]);
            ls[c][dz][yy][xx] = nv;
            xin[ga] = nv;
        }
        __syncthreads();
#pragma unroll 1
        for (int c = 0; c < 8; ++c) {
            int ci = cc * 8 + c;
#pragma unroll
            for (int tap = 0; tap < 8; ++tap) {
                int dz = tap >> 2, dy = (tap >> 1) & 1, dx = tap & 1;
                float w[8];
#pragma unroll
                for (int j = 0; j < 8; ++j)
                    w[j] = dw[((size_t)(cog * 8 + j) * CO + ci) * 8 + tap];
#pragma unroll
                for (int yo = 0; yo < 4; ++yo) {
                    float xv = ls[c][dz][yo * 2 + dy][2 * xo + dx];
#pragma unroll
                    for (int j = 0; j < 8; ++j) acc[yo][j] += w[j] * xv;
                }
            }
        }
        __syncthreads();
    }
#pragma unroll
    for (int yo = 0; yo < 4; ++yo)
#pragma unroll
        for (int j = 0; j < 8; ++j)
            out[((size_t)(n * CO + cog * 8 + j) * 32 + z) * 1024 + (yt * 4 + yo) * 32 + xo]
                = acc[yo][j];

    // y-stats partials
    float s1[8], s2[8];
#pragma unroll
    for (int j = 0; j < 8; ++j) { s1[j] = 0.f; s2[j] = 0.f; }
#pragma unroll
    for (int yo = 0; yo < 4; ++yo)
#pragma unroll
        for (int j = 0; j < 8; ++j) {
            float v = acc[yo][j];
            s1[j] += v; s2[j] += v * v;
        }
#pragma unroll
    for (int o = 1; o < 32; o <<= 1)
#pragma unroll
        for (int j = 0; j < 8; ++j) {
            s1[j] += __shfl_xor(s1[j], o, 64);
            s2[j] += __shfl_xor(s2[j], o, 64);
        }
    if (xo == 0) {
        int cb = b & 255;
#pragma unroll
        for (int j = 0; j < 8; ++j) {
            int co = cog * 8 + j;
            part[((size_t)(n * 2 + 0) * 64 + co) * 256 + cb] = s1[j];
            part[((size_t)(n * 2 + 1) * 64 + co) * 256 + cb] = s2[j];
        }
    }
}

// -------------------------------------------------------------- launch ----
extern "C" void kernel_launch(void* const* d_in, const int* in_sizes, int n_in,
                              void* d_out, int out_size, void* d_ws, size_t ws_size,
                              hipStream_t stream) {
    const float* x      = (const float*)d_in[0];
    const float* t      = (const float*)d_in[1];
    const float* l1_c5  = (const float*)d_in[2];
    const float* l1_c3  = (const float*)d_in[3];
    const float* l1_c1  = (const float*)d_in[4];
    const float* l1_a3  = (const float*)d_in[5];
    const float* l1_a5  = (const float*)d_in[6];
    const float* l1_gw  = (const float*)d_in[7];
    const float* l1_gb  = (const float*)d_in[8];
    const float* l1_ga  = (const float*)d_in[9];
    const float* l1_be  = (const float*)d_in[10];
    const float* l2_c5  = (const float*)d_in[11];
    const float* l2_c3  = (const float*)d_in[12];
    const float* l2_c1  = (const float*)d_in[13];
    const float* l2_a3  = (const float*)d_in[14];
    const float* l2_a5  = (const float*)d_in[15];
    const float* l2_gw  = (const float*)d_in[16];
    const float* l2_gb  = (const float*)d_in[17];
    const float* l2_ga  = (const float*)d_in[18];
    const float* l2_be  = (const float*)d_in[19];
    const float* down_w = (const float*)d_in[20];
    const float* dn_ga  = (const float*)d_in[21];
    const float* dn_be  = (const float*)d_in[22];

    char* ws = (char*)d_ws;
    unsigned short* xcl = (unsigned short*)(ws);                  // 33,554,432 B
    unsigned short* h2  = (unsigned short*)(ws + 33554432);       // 67,108,864 B
    unsigned short* w1  = (unsigned short*)(ws + 100663296);      //  1,024,000 B
    unsigned short* w2  = (unsigned short*)(ws + 101687296);      //  2,048,000 B
    float* g1    = (float*)(ws + 103735296);
    float* g2    = (float*)(ws + 103737856);
    float* st1   = (float*)(ws + 103740416);
    float* st2   = (float*)(ws + 103741440);
    float* st3   = (float*)(ws + 103742464);
    float* part1 = (float*)(ws + 103743488);                      //  2,097,152 B (256 rows x 2048 x 4B)
    float* part2 = (float*)(ws + 105840640);                      //  2,097,152 B
    float* part3 = (float*)(ws + 107937792);                      //    262,144 B
    float* zbuf  = (float*)(ws + 108199936);                      //        256 B

    float* yout  = (float*)d_out;
    float* xskip = (float*)d_out + Y_SZ;

    gate_kernel<<<1, 192, 0, stream>>>(t, l1_gw, l1_gb, g1, zbuf);
    gate_kernel<<<1, 192, 0, stream>>>(t, l2_gw, l2_gb, g2, zbuf);
    synth_kernel<32><<<(NB * CO * 32 * 125 + 255) / 256, 256, 0, stream>>>(
        g1, l1_c5, l1_c3, l1_c1, l1_a3, l1_a5, w1);
    synth_kernel<64><<<(NB * CO * 64 * 125 + 255) / 256, 256, 0, stream>>>(
        g2, l2_c5, l2_c3, l2_c1, l2_a3, l2_a5, w2);
    x_to_cl<<<2048, 256, 0, stream>>>(x, xcl);

    // layer 1: conv (bf16 CL in -> bf16 CL raw out) + fused stats partials
    conv5_mfma<32, true, 2048><<<2048, 512, 0, stream>>>(xcl, w1, h2, part1, zbuf);
    stats_fin<2048><<<128, 256, 0, stream>>>(part1, st1, 1.f / SP);
    norm_mish_cl_kernel<<<16384, 256, 0, stream>>>(h2, st1, l1_ga, l1_be);

    // layer 2: conv (bf16 CL in -> f32 NCDHW raw into x_skip) + partials
    conv5_mfma<64, false, 2048><<<2048, 512, 0, stream>>>(h2, w2, xskip, part2, zbuf);
    stats_fin<2048><<<128, 256, 0, stream>>>(part2, st2, 1.f / SP);

    // downsample: fused norm+mish(x_skip, in place) + conv + y-stats partials
    down_conv_kernel<<<NB * 32 * 8, 256, 0, stream>>>(xskip, down_w, st2, l2_ga, l2_be,
                                                      yout, part3);
    stats_fin<256><<<128, 256, 0, stream>>>(part3, st3, 1.f / 32768.f);
    norm_mish_kernel<15><<<(NC * 32768 / 4 + 255) / 256, 256, 0, stream>>>(
        yout, st3, dn_ga, dn_be, NC * 32768 / 4);
}

// Round 11
// 849.682 us; speedup vs baseline: 3.9035x; 1.0021x over previous
//
#include <hip/hip_runtime.h>
#include <cstdint>
#include <cstddef>

constexpr int NB  = 2;
constexpr int CO  = 64;
constexpr int DIM = 64;
constexpr int SP  = DIM * DIM * DIM;       // 262144
constexpr int NC  = NB * CO;               // 128
constexpr int Y_SZ = NB * CO * 32 * 32 * 32;

typedef float f32x4 __attribute__((ext_vector_type(4)));
typedef short s16x8 __attribute__((ext_vector_type(8)));

__device__ __forceinline__ unsigned short f2bf(float f) {
    unsigned int u = __float_as_uint(f);
    unsigned int r = (u + 0x7fffu + ((u >> 16) & 1u)) >> 16;
    return (unsigned short)r;
}
__device__ __forceinline__ float bf2f(unsigned short u) {
    return __uint_as_float((unsigned int)u << 16);
}
__device__ __forceinline__ unsigned int pack2(float a, float b) {
    return (unsigned int)f2bf(a) | ((unsigned int)f2bf(b) << 16);
}
// mish(x) = x * tanh(softplus(x)) = x*(e^2+2e)/(e^2+2e+2), e = exp(x)
__device__ __forceinline__ float mish_f(float x) {
    float e = __expf(x);
    float num = e * (e + 2.f);
    float r = x * num * __builtin_amdgcn_rcpf(num + 2.f);
    return (x > 15.f) ? x : r;
}

__device__ __forceinline__ void gload_lds16(const void* g, void* l) {
    __builtin_amdgcn_global_load_lds(
        (const __attribute__((address_space(1))) unsigned int*)g,
        (__attribute__((address_space(3))) unsigned int*)l, 16, 0, 0);
}

// -------------------------------------------------------- gate (+zero) ----
__global__ void gate_kernel(const float* __restrict__ t, const float* __restrict__ gw,
                            const float* __restrict__ gb, float* __restrict__ g,
                            float* __restrict__ zbuf) {
    int tid = threadIdx.x;
    if (tid >= 128) { if (tid < 192) zbuf[tid - 128] = 0.f; return; }
    int n = tid >> 6, co = tid & 63;
    float tl[10];
#pragma unroll
    for (int k = 0; k < 10; ++k) tl[k] = t[n * 10 + k];
    float l[5];
#pragma unroll
    for (int e = 0; e < 5; ++e) {
        int row = e * CO + co;
        float acc = gb[row];
#pragma unroll
        for (int k = 0; k < 10; ++k) acc += tl[k] * gw[row * 10 + k];
        l[e] = acc;
    }
    float m = l[0];
#pragma unroll
    for (int e = 1; e < 5; ++e) m = fmaxf(m, l[e]);
    float s = 0.f;
#pragma unroll
    for (int e = 0; e < 5; ++e) { l[e] = expf(l[e] - m); s += l[e]; }
    float inv = 1.f / s;
#pragma unroll
    for (int e = 0; e < 5; ++e) g[(n * 5 + e) * CO + co] = l[e] * inv;
}

// --------------------------------------------------------------- synth ----
// wbuf (bf16): [n][dz(5)][cich(CI/32)][t(25)][co(64)][cil(32)]
template <int CI>
__global__ void synth_kernel(const float* __restrict__ g,
                             const float* __restrict__ c5, const float* __restrict__ c3,
                             const float* __restrict__ c1, const float* __restrict__ a3,
                             const float* __restrict__ a5, unsigned short* __restrict__ wbuf) {
    int idx = blockIdx.x * 256 + threadIdx.x;
    constexpr int TOTAL = NB * CO * CI * 125;
    if (idx >= TOTAL) return;
    int tap = idx % 125;
    int ci  = (idx / 125) % CI;
    int co  = (idx / (125 * CI)) % CO;
    int n   = idx / (125 * CI * CO);
    const float* gn = g + n * 5 * CO;
    float g0 = gn[0 * CO + co], g1 = gn[1 * CO + co], g2 = gn[2 * CO + co],
          g3 = gn[3 * CO + co], g4 = gn[4 * CO + co];
    int dz = tap / 25, dy = (tap / 5) % 5, dx = tap % 5;
    int oc = co * CI + ci;
    float v = g0 * c5[(size_t)oc * 125 + tap] + g4 * a5[oc] * (1.f / 125.f);
    if (dz >= 1 && dz <= 3 && dy >= 1 && dy <= 3 && dx >= 1 && dx <= 3)
        v += g1 * c3[(size_t)oc * 27 + (dz - 1) * 9 + (dy - 1) * 3 + (dx - 1)]
           + g3 * a3[oc] * (1.f / 27.f);
    if (dz == 2 && dy == 2 && dx == 2) v += g2 * c1[oc];
    int t = (dy * 5 + dx);
    int cich = ci >> 5, cil = ci & 31;
    wbuf[((((size_t)(n * 5 + dz) * (CI / 32) + cich) * 25 + t) * 64 + co) * 32 + cil] = f2bf(v);
}

// -------------------------------------------------------------- x->CL -----
__global__ __launch_bounds__(256) void x_to_cl(const float* __restrict__ x,
                                               unsigned short* __restrict__ xcl) {
    __shared__ float ld[32][256];
    int b = blockIdx.x;                   // 2048 = n(2) x 1024
    int n = b >> 10;
    size_t base = (size_t)(b & 1023) * 256;
    int tid = threadIdx.x;
    const float* xp = x + (size_t)n * 32 * SP + base + tid;
#pragma unroll
    for (int c = 0; c < 32; ++c) ld[c][tid] = xp[(size_t)c * SP];
    __syncthreads();
    uint4* op = (uint4*)(xcl + ((size_t)n * SP + base) * 32);
#pragma unroll
    for (int r = 0; r < 4; ++r) {
        int idx = r * 256 + tid;
        int px = idx >> 2, q = idx & 3;
        uint4 o;
        o.x = pack2(ld[q * 8 + 0][px], ld[q * 8 + 1][px]);
        o.y = pack2(ld[q * 8 + 2][px], ld[q * 8 + 3][px]);
        o.z = pack2(ld[q * 8 + 4][px], ld[q * 8 + 5][px]);
        o.w = pack2(ld[q * 8 + 6][px], ld[q * 8 + 7][px]);
        op[idx] = o;
    }
}

// ----------------------------------------------------------- MFMA conv ----
// Input bf16 channel-last [n][zyx][CI]. Block (512 thr): (n,z,yt,xt) ->
// 64co x 16y x 16x. Wave (yh 0..1, cq 0..3): 8 y-rows x 16 co.
// T4 counted-vmcnt pipeline: 3 LDS buffers, 2-stage-ahead global_load_lds
// prefetch, raw s_barrier + s_waitcnt vmcnt(L) (never 0 in steady state).
// Per-wave load counts: wave 0 = 4/stage, waves 1-7 = 3/stage.
template <int CI, bool OUT_CL, int PCH>
__global__ __launch_bounds__(512, 4) void conv5_mfma(const unsigned short* __restrict__ xin,
                                                     const unsigned short* __restrict__ wbuf,
                                                     void* __restrict__ outp,
                                                     float* __restrict__ part,
                                                     const void* __restrict__ zbuf) {
    constexpr int NCH = CI / 32;
    constexpr int NS  = 5 * NCH;
    __shared__ __align__(16) unsigned short lds[3][12800];   // 3 x 25.6 KB

    const int b   = blockIdx.x;
    const int xt  = b & 3;
    const int yt  = (b >> 2) & 3;
    const int z   = (b >> 4) & 63;
    const int n   = b >> 10;
    const int tid = threadIdx.x;
    const int lane = tid & 63, wv = tid >> 6;
    const int xl = lane & 15, kh = lane >> 4;
    const int yh = wv >> 2, cq = wv & 3;

    f32x4 acc[8];
#pragma unroll
    for (int pt = 0; pt < 8; ++pt)
#pragma unroll
        for (int j = 0; j < 4; ++j) acc[pt][j] = 0.f;

    // staging geometry: LDS slot idx = tid + r*512 (linear dest, 16B each)
    long goff[4]; int gval[4];
#pragma unroll
    for (int r = 0; r < 4; ++r) {
        int idx = tid + r * 512;
        int p = idx >> 2, khs = idx & 3;
        int xx = p % 20, yy = p / 20;
        int yi = yt * 16 - 2 + yy, xi = xt * 16 - 2 + xx;
        gval[r] = ((unsigned)yi < 64u) && ((unsigned)xi < 64u);
        goff[r] = ((long)(yi * 64 + xi) * CI + khs * 8) * 2;
    }

    auto stage = [&](int s, int buf) {
        int dz = s / NCH, cich = s % NCH;
        int zi = z + dz - 2;
        bool zok = (unsigned)zi < 64u;
        const char* pb = (const char*)xin
                       + ((size_t)(n * SP + zi * 4096) * CI + cich * 32) * 2;
        char* lb = (char*)&lds[buf][0];
#pragma unroll
        for (int r = 0; r < 4; ++r) {
            int idx = tid + r * 512;
            if (idx < 1600) {
                const void* g = (zok && gval[r]) ? (const void*)(pb + goff[r]) : zbuf;
                gload_lds16(g, lb + idx * 16);
            }
        }
    };

    auto compute = [&](int s, int buf) {
        int dz = s / NCH, cich = s % NCH;
        const unsigned short* wp = wbuf
            + ((size_t)((n * 5 + dz) * NCH + cich) * 25) * 2048
            + cq * 512 + xl * 32 + kh * 8;
        const char* src = (const char*)&lds[buf][0];
        __builtin_amdgcn_s_setprio(1);
#pragma unroll 1
        for (int dx = 0; dx < 5; ++dx) {
            int xx = xl + dx;
            s16x8 fr[12];
#pragma unroll
            for (int r = 0; r < 12; ++r) {
                int row = yh * 8 + r;
                fr[r] = *(const s16x8*)(src + (size_t)(row * 20 + xx) * 64 + kh * 16);
            }
#pragma unroll
            for (int dy = 0; dy < 5; ++dy) {
                s16x8 a = *(const s16x8*)(wp + (size_t)(dy * 5 + dx) * 2048);
#pragma unroll
                for (int pt = 0; pt < 8; ++pt)
                    acc[pt] = __builtin_amdgcn_mfma_f32_16x16x32_bf16(
                        a, fr[pt + dy], acc[pt], 0, 0, 0);
            }
        }
        __builtin_amdgcn_s_setprio(0);
    };

    // prologue: 2 stages in flight
    stage(0, 0);
    if (NS > 1) stage(1, 1);
#pragma unroll 1
    for (int s = 0; s < NS; ++s) {
        // wait: own stage-s loads complete (allow s+1/s+2 to stay in flight)
        if (s == NS - 1) {
            asm volatile("s_waitcnt vmcnt(0)" ::: "memory");
        } else if (wv == 0) {
            asm volatile("s_waitcnt vmcnt(4)" ::: "memory");
        } else {
            asm volatile("s_waitcnt vmcnt(3)" ::: "memory");
        }
        __builtin_amdgcn_s_barrier();        // all waves: stage s ready; all done with compute(s-1)
        __builtin_amdgcn_sched_barrier(0);
        if (s + 2 < NS) stage(s + 2, (s + 2) % 3);   // overwrites buf[(s-1)%3] — safe after barrier
        compute(s, s % 3);
    }
    __syncthreads();   // epilogue reuses LDS

    // ---- fused instance-norm partial sums -> part[n][s][co][PCH] ----
    {
        float s1[4], s2[4];
#pragma unroll
        for (int j = 0; j < 4; ++j) { s1[j] = 0.f; s2[j] = 0.f; }
#pragma unroll
        for (int pt = 0; pt < 8; ++pt)
#pragma unroll
            for (int j = 0; j < 4; ++j) {
                float v = acc[pt][j];
                s1[j] += v; s2[j] += v * v;
            }
#pragma unroll
        for (int o = 1; o < 16; o <<= 1)
#pragma unroll
            for (int j = 0; j < 4; ++j) {
                s1[j] += __shfl_xor(s1[j], o, 64);
                s2[j] += __shfl_xor(s2[j], o, 64);
            }
        if (xl == 0) {
            int co = cq * 16 + kh * 4;
            int cb = (b & 1023) * 2 + yh;
#pragma unroll
            for (int j = 0; j < 4; ++j) {
                part[((size_t)(n * 2 + 0) * 64 + co + j) * PCH + cb] = s1[j];
                part[((size_t)(n * 2 + 1) * 64 + co + j) * PCH + cb] = s2[j];
            }
        }
    }

    if (OUT_CL) {
        // transpose via XOR-swizzled LDS [pix(256)][co(64)] bf16 -> coalesced
        char* tb = (char*)&lds[0][0];     // 32 KB
#pragma unroll
        for (int pt = 0; pt < 8; ++pt) {
            int pix = (yh * 8 + pt) * 16 + xl;
            unsigned int ad = ((unsigned)(pix * 128 + cq * 32 + kh * 8))
                              ^ ((unsigned)(pix & 7) << 4);
            *(unsigned int*)(tb + ad)     = pack2(acc[pt][0], acc[pt][1]);
            *(unsigned int*)(tb + ad + 4) = pack2(acc[pt][2], acc[pt][3]);
        }
        __syncthreads();
#pragma unroll
        for (int it = 0; it < 4; ++it) {
            int idx = it * 512 + tid;
            int pix = idx >> 3, ch = idx & 7;
            uint4 v = *(const uint4*)(tb + (((unsigned)idx * 16)
                                            ^ ((unsigned)(pix & 7) << 4)));
            int y = yt * 16 + (pix >> 4), x = xt * 16 + (pix & 15);
            *(uint4*)((unsigned short*)outp
                      + ((size_t)(n * SP + z * 4096 + y * 64 + x) * 64 + ch * 8)) = v;
        }
    } else {
        float* op = (float*)outp;
#pragma unroll
        for (int pt = 0; pt < 8; ++pt) {
            int y = yt * 16 + yh * 8 + pt;
#pragma unroll
            for (int j = 0; j < 4; ++j)
                op[((size_t)(n * 64 + cq * 16 + kh * 4 + j) * 64 + z) * 4096
                   + y * 64 + xt * 16 + xl] = acc[pt][j];
        }
    }
}

// ------------------------------------------------- stats finalize ---------
// part: [n][s][co][CH] contiguous rows. grid = 128 (n*64+co), 256 thr.
template <int CH>
__global__ void stats_fin(const float* __restrict__ part, float* __restrict__ st,
                          float invS) {
    int blk = blockIdx.x;
    int n = blk >> 6, co = blk & 63;
    int tid = threadIdx.x;
    const float* ps = part + ((size_t)(n * 2 + 0) * 64 + co) * CH;
    const float* pq = part + ((size_t)(n * 2 + 1) * 64 + co) * CH;
    float s1 = 0.f, s2 = 0.f;
    for (int i = tid; i < CH; i += 256) { s1 += ps[i]; s2 += pq[i]; }
#pragma unroll
    for (int o = 1; o < 64; o <<= 1) {
        s1 += __shfl_xor(s1, o, 64);
        s2 += __shfl_xor(s2, o, 64);
    }
    __shared__ float sh1[4], sh2[4];
    if ((tid & 63) == 0) { sh1[tid >> 6] = s1; sh2[tid >> 6] = s2; }
    __syncthreads();
    if (tid == 0) {
        float a = sh1[0] + sh1[1] + sh1[2] + sh1[3];
        float q = sh2[0] + sh2[1] + sh2[2] + sh2[3];
        float mean = a * invS;
        float var  = q * invS - mean * mean;
        st[(n * 64 + co) * 2]     = mean;
        st[(n * 64 + co) * 2 + 1] = rsqrtf(var + 1e-5f);
    }
}

// -------------------------------------- norm+mish in-place, channel-last --
__global__ void norm_mish_cl_kernel(unsigned short* __restrict__ h,
                                    const float* __restrict__ st,
                                    const float* __restrict__ gamma,
                                    const float* __restrict__ beta) {
    size_t idx = (size_t)blockIdx.x * 256 + threadIdx.x;   // NB*SP*8 items
    uint4 v = ((uint4*)h)[idx];
    int c0 = ((int)(idx & 7)) * 8;
    size_t pix = idx >> 3;
    int n = (int)(pix >> 18);
    unsigned int* pv = &v.x;
#pragma unroll
    for (int q = 0; q < 4; ++q) {
        unsigned int wv = pv[q];
        unsigned int out = 0;
#pragma unroll
        for (int hv = 0; hv < 2; ++hv) {
            int c = c0 + 2 * q + hv;
            int nc = n * 64 + c;
            float val = bf2f((unsigned short)((wv >> (16 * hv)) & 0xffffu));
            float xh = (val - st[nc * 2]) * st[nc * 2 + 1] * gamma[c] + beta[c];
            out |= ((unsigned int)f2bf(mish_f(xh))) << (16 * hv);
        }
        pv[q] = out;
    }
    ((uint4*)h)[idx] = v;
}

// ----------------------------------------------------------- norm+mish ----
template <int SHIFT>
__global__ void norm_mish_kernel(float* __restrict__ buf, const float* __restrict__ stats,
                                 const float* __restrict__ gamma, const float* __restrict__ beta,
                                 int total4) {
    int idx = blockIdx.x * 256 + threadIdx.x;
    if (idx >= total4) return;
    float4 v = reinterpret_cast<float4*>(buf)[idx];
    int nc = idx >> (SHIFT - 2);
    int c  = nc & 63;
    float mean = stats[nc * 2], inv = stats[nc * 2 + 1];
    float ga = gamma[c], be = beta[c];
    float* pv = &v.x;
#pragma unroll
    for (int k = 0; k < 4; ++k) {
        float xh = (pv[k] - mean) * inv * ga + be;
        pv[k] = mish_f(xh);
    }
    reinterpret_cast<float4*>(buf)[idx] = v;
}

// ----------------------------------------------------------- down conv ----
// Fused: reads RAW xskip, applies norm+mish (st2), writes normalized back,
// 2x2x2 stride-2 conv, writes raw y + y-stats partials [n][s][co][256].
__global__ __launch_bounds__(256) void down_conv_kernel(float* __restrict__ xin,
                                                        const float* __restrict__ dw,
                                                        const float* __restrict__ st,
                                                        const float* __restrict__ gamma,
                                                        const float* __restrict__ beta,
                                                        float* __restrict__ out,
                                                        float* __restrict__ part) {
    __shared__ float ls[8][2][8][64];
    int b   = blockIdx.x;
    int yt  = b & 7;
    int z   = (b >> 3) & 31;
    int n   = b >> 8;
    int tid = threadIdx.x;
    int xo  = tid & 31;
    int cog = tid >> 5;

    float acc[4][8];
#pragma unroll
    for (int yo = 0; yo < 4; ++yo)
#pragma unroll
        for (int j = 0; j < 8; ++j) acc[yo][j] = 0.f;

    for (int cc = 0; cc < 8; ++cc) {
        for (int idx = tid; idx < 8192; idx += 256) {
            int xx = idx & 63;
            int yy = (idx >> 6) & 7;
            int dz = (idx >> 9) & 1;
            int c  = idx >> 10;
            int ci = cc * 8 + c;
            size_t ga = ((size_t)(n * CO + ci) * 64 + 2 * z + dz) * 4096
                      + (yt * 8 + yy) * 64 + xx;
            float v = xin[ga];
            int nc = n * 64 + ci;
            float nv = mish_f((v - st[nc * 2]) * st[nc * 2 + 1] * gamma[ci] + beta[ci]);
            ls[c][dz][yy][xx] = nv;
            xin[ga] = nv;
        }
        __syncthreads();
#pragma unroll 1
        for (int c = 0; c < 8; ++c) {
            int ci = cc * 8 + c;
#pragma unroll
            for (int tap = 0; tap < 8; ++tap) {
                int dz = tap >> 2, dy = (tap >> 1) & 1, dx = tap & 1;
                float w[8];
#pragma unroll
                for (int j = 0; j < 8; ++j)
                    w[j] = dw[((size_t)(cog * 8 + j) * CO + ci) * 8 + tap];
#pragma unroll
                for (int yo = 0; yo < 4; ++yo) {
                    float xv = ls[c][dz][yo * 2 + dy][2 * xo + dx];
#pragma unroll
                    for (int j = 0; j < 8; ++j) acc[yo][j] += w[j] * xv;
                }
            }
        }
        __syncthreads();
    }
#pragma unroll
    for (int yo = 0; yo < 4; ++yo)
#pragma unroll
        for (int j = 0; j < 8; ++j)
            out[((size_t)(n * CO + cog * 8 + j) * 32 + z) * 1024 + (yt * 4 + yo) * 32 + xo]
                = acc[yo][j];

    // y-stats partials
    float s1[8], s2[8];
#pragma unroll
    for (int j = 0; j < 8; ++j) { s1[j] = 0.f; s2[j] = 0.f; }
#pragma unroll
    for (int yo = 0; yo < 4; ++yo)
#pragma unroll
        for (int j = 0; j < 8; ++j) {
            float v = acc[yo][j];
            s1[j] += v; s2[j] += v * v;
        }
#pragma unroll
    for (int o = 1; o < 32; o <<= 1)
#pragma unroll
        for (int j = 0; j < 8; ++j) {
            s1[j] += __shfl_xor(s1[j], o, 64);
            s2[j] += __shfl_xor(s2[j], o, 64);
        }
    if (xo == 0) {
        int cb = b & 255;
#pragma unroll
        for (int j = 0; j < 8; ++j) {
            int co = cog * 8 + j;
            part[((size_t)(n * 2 + 0) * 64 + co) * 256 + cb] = s1[j];
            part[((size_t)(n * 2 + 1) * 64 + co) * 256 + cb] = s2[j];
        }
    }
}

// -------------------------------------------------------------- launch ----
extern "C" void kernel_launch(void* const* d_in, const int* in_sizes, int n_in,
                              void* d_out, int out_size, void* d_ws, size_t ws_size,
                              hipStream_t stream) {
    const float* x      = (const float*)d_in[0];
    const float* t      = (const float*)d_in[1];
    const float* l1_c5  = (const float*)d_in[2];
    const float* l1_c3  = (const float*)d_in[3];
    const float* l1_c1  = (const float*)d_in[4];
    const float* l1_a3  = (const float*)d_in[5];
    const float* l1_a5  = (const float*)d_in[6];
    const float* l1_gw  = (const float*)d_in[7];
    const float* l1_gb  = (const float*)d_in[8];
    const float* l1_ga  = (const float*)d_in[9];
    const float* l1_be  = (const float*)d_in[10];
    const float* l2_c5  = (const float*)d_in[11];
    const float* l2_c3  = (const float*)d_in[12];
    const float* l2_c1  = (const float*)d_in[13];
    const float* l2_a3  = (const float*)d_in[14];
    const float* l2_a5  = (const float*)d_in[15];
    const float* l2_gw  = (const float*)d_in[16];
    const float* l2_gb  = (const float*)d_in[17];
    const float* l2_ga  = (const float*)d_in[18];
    const float* l2_be  = (const float*)d_in[19];
    const float* down_w = (const float*)d_in[20];
    const float* dn_ga  = (const float*)d_in[21];
    const float* dn_be  = (const float*)d_in[22];

    char* ws = (char*)d_ws;
    unsigned short* xcl = (unsigned short*)(ws);                  // 33,554,432 B
    unsigned short* h2  = (unsigned short*)(ws + 33554432);       // 67,108,864 B
    unsigned short* w1  = (unsigned short*)(ws + 100663296);      //  1,024,000 B
    unsigned short* w2  = (unsigned short*)(ws + 101687296);      //  2,048,000 B
    float* g1    = (float*)(ws + 103735296);
    float* g2    = (float*)(ws + 103737856);
    float* st1   = (float*)(ws + 103740416);
    float* st2   = (float*)(ws + 103741440);
    float* st3   = (float*)(ws + 103742464);
    float* part1 = (float*)(ws + 103743488);                      //  2,097,152 B
    float* part2 = (float*)(ws + 105840640);                      //  2,097,152 B
    float* part3 = (float*)(ws + 107937792);                      //    262,144 B
    float* zbuf  = (float*)(ws + 108199936);                      //        256 B

    float* yout  = (float*)d_out;
    float* xskip = (float*)d_out + Y_SZ;

    gate_kernel<<<1, 192, 0, stream>>>(t, l1_gw, l1_gb, g1, zbuf);
    gate_kernel<<<1, 192, 0, stream>>>(t, l2_gw, l2_gb, g2, zbuf);
    synth_kernel<32><<<(NB * CO * 32 * 125 + 255) / 256, 256, 0, stream>>>(
        g1, l1_c5, l1_c3, l1_c1, l1_a3, l1_a5, w1);
    synth_kernel<64><<<(NB * CO * 64 * 125 + 255) / 256, 256, 0, stream>>>(
        g2, l2_c5, l2_c3, l2_c1, l2_a3, l2_a5, w2);
    x_to_cl<<<2048, 256, 0, stream>>>(x, xcl);

    // layer 1: conv (bf16 CL in -> bf16 CL raw out) + fused stats partials
    conv5_mfma<32, true, 2048><<<2048, 512, 0, stream>>>(xcl, w1, h2, part1, zbuf);
    stats_fin<2048><<<128, 256, 0, stream>>>(part1, st1, 1.f / SP);
    norm_mish_cl_kernel<<<16384, 256, 0, stream>>>(h2, st1, l1_ga, l1_be);

    // layer 2: conv (bf16 CL in -> f32 NCDHW raw into x_skip) + partials
    conv5_mfma<64, false, 2048><<<2048, 512, 0, stream>>>(h2, w2, xskip, part2, zbuf);
    stats_fin<2048><<<128, 256, 0, stream>>>(part2, st2, 1.f / SP);

    // downsample: fused norm+mish(x_skip, in place) + conv + y-stats partials
    down_conv_kernel<<<NB * 32 * 8, 256, 0, stream>>>(xskip, down_w, st2, l2_ga, l2_be,
                                                      yout, part3);
    stats_fin<256><<<128, 256, 0, stream>>>(part3, st3, 1.f / 32768.f);
    norm_mish_kernel<15><<<(NC * 32768 / 4 + 255) / 256, 256, 0, stream>>>(
        yout, st3, dn_ga, dn_be, NC * 32768 / 4);
}

// Round 12
// 798.775 us; speedup vs baseline: 4.1523x; 1.0637x over previous
//
#include <hip/hip_runtime.h>
#include <cstdint>
#include <cstddef>

constexpr int NB  = 2;
constexpr int CO  = 64;
constexpr int DIM = 64;
constexpr int SP  = DIM * DIM * DIM;       // 262144
constexpr int NC  = NB * CO;               // 128
constexpr int Y_SZ = NB * CO * 32 * 32 * 32;

typedef float f32x4 __attribute__((ext_vector_type(4)));
typedef short s16x8 __attribute__((ext_vector_type(8)));

__device__ __forceinline__ unsigned short f2bf(float f) {
    unsigned int u = __float_as_uint(f);
    unsigned int r = (u + 0x7fffu + ((u >> 16) & 1u)) >> 16;
    return (unsigned short)r;
}
__device__ __forceinline__ float bf2f(unsigned short u) {
    return __uint_as_float((unsigned int)u << 16);
}
__device__ __forceinline__ unsigned int pack2(float a, float b) {
    return (unsigned int)f2bf(a) | ((unsigned int)f2bf(b) << 16);
}
// mish(x) = x * tanh(softplus(x)) = x*(e^2+2e)/(e^2+2e+2), e = exp(x)
__device__ __forceinline__ float mish_f(float x) {
    float e = __expf(x);
    float num = e * (e + 2.f);
    float r = x * num * __builtin_amdgcn_rcpf(num + 2.f);
    return (x > 15.f) ? x : r;
}

__device__ __forceinline__ void gload_lds16(const void* g, void* l) {
    __builtin_amdgcn_global_load_lds(
        (const __attribute__((address_space(1))) unsigned int*)g,
        (__attribute__((address_space(3))) unsigned int*)l, 16, 0, 0);
}

// ------------------------------------------------ gate both layers + zero --
__global__ void gate2_kernel(const float* __restrict__ t,
                             const float* __restrict__ gw1, const float* __restrict__ gb1,
                             float* __restrict__ g1,
                             const float* __restrict__ gw2, const float* __restrict__ gb2,
                             float* __restrict__ g2,
                             float* __restrict__ zbuf) {
    int tid = threadIdx.x;                 // 0..255
    if (tid < 64) zbuf[tid] = 0.f;
    int layer = tid >> 7;                  // 0: layer1, 1: layer2
    int lt = tid & 127;
    int n = lt >> 6, co = lt & 63;
    const float* gw = layer ? gw2 : gw1;
    const float* gb = layer ? gb2 : gb1;
    float* g = layer ? g2 : g1;
    float tl[10];
#pragma unroll
    for (int k = 0; k < 10; ++k) tl[k] = t[n * 10 + k];
    float l[5];
#pragma unroll
    for (int e = 0; e < 5; ++e) {
        int row = e * CO + co;
        float acc = gb[row];
#pragma unroll
        for (int k = 0; k < 10; ++k) acc += tl[k] * gw[row * 10 + k];
        l[e] = acc;
    }
    float m = l[0];
#pragma unroll
    for (int e = 1; e < 5; ++e) m = fmaxf(m, l[e]);
    float s = 0.f;
#pragma unroll
    for (int e = 0; e < 5; ++e) { l[e] = expf(l[e] - m); s += l[e]; }
    float inv = 1.f / s;
#pragma unroll
    for (int e = 0; e < 5; ++e) g[(n * 5 + e) * CO + co] = l[e] * inv;
}

// --------------------------------------------------------------- synth ----
// wbuf (bf16): [n][dz(5)][cich(CI/32)][t(25)][co(64)][cil(32)]
template <int CI>
__device__ __forceinline__ void synth_one(int idx, const float* __restrict__ g,
                                          const float* __restrict__ c5, const float* __restrict__ c3,
                                          const float* __restrict__ c1, const float* __restrict__ a3,
                                          const float* __restrict__ a5,
                                          unsigned short* __restrict__ wbuf) {
    int tap = idx % 125;
    int ci  = (idx / 125) % CI;
    int co  = (idx / (125 * CI)) % CO;
    int n   = idx / (125 * CI * CO);
    const float* gn = g + n * 5 * CO;
    float g0 = gn[0 * CO + co], g1 = gn[1 * CO + co], g2 = gn[2 * CO + co],
          g3 = gn[3 * CO + co], g4 = gn[4 * CO + co];
    int dz = tap / 25, dy = (tap / 5) % 5, dx = tap % 5;
    int oc = co * CI + ci;
    float v = g0 * c5[(size_t)oc * 125 + tap] + g4 * a5[oc] * (1.f / 125.f);
    if (dz >= 1 && dz <= 3 && dy >= 1 && dy <= 3 && dx >= 1 && dx <= 3)
        v += g1 * c3[(size_t)oc * 27 + (dz - 1) * 9 + (dy - 1) * 3 + (dx - 1)]
           + g3 * a3[oc] * (1.f / 27.f);
    if (dz == 2 && dy == 2 && dx == 2) v += g2 * c1[oc];
    int t = (dy * 5 + dx);
    int cich = ci >> 5, cil = ci & 31;
    wbuf[((((size_t)(n * 5 + dz) * (CI / 32) + cich) * 25 + t) * 64 + co) * 32 + cil] = f2bf(v);
}

__global__ void synth2_kernel(const float* __restrict__ g1,
                              const float* __restrict__ c51, const float* __restrict__ c31,
                              const float* __restrict__ c11, const float* __restrict__ a31,
                              const float* __restrict__ a51, unsigned short* __restrict__ w1,
                              const float* __restrict__ g2,
                              const float* __restrict__ c52, const float* __restrict__ c32,
                              const float* __restrict__ c12, const float* __restrict__ a32,
                              const float* __restrict__ a52, unsigned short* __restrict__ w2) {
    constexpr int T1 = NB * CO * 32 * 125;   // 512,000
    constexpr int T2 = NB * CO * 64 * 125;   // 1,024,000
    int idx = blockIdx.x * 256 + threadIdx.x;
    if (idx < T1)
        synth_one<32>(idx, g1, c51, c31, c11, a31, a51, w1);
    else if (idx < T1 + T2)
        synth_one<64>(idx - T1, g2, c52, c32, c12, a32, a52, w2);
}

// -------------------------------------------------------------- x->CL -----
__global__ __launch_bounds__(256) void x_to_cl(const float* __restrict__ x,
                                               unsigned short* __restrict__ xcl) {
    __shared__ float ld[32][256];
    int b = blockIdx.x;                   // 2048 = n(2) x 1024
    int n = b >> 10;
    size_t base = (size_t)(b & 1023) * 256;
    int tid = threadIdx.x;
    const float* xp = x + (size_t)n * 32 * SP + base + tid;
#pragma unroll
    for (int c = 0; c < 32; ++c) ld[c][tid] = xp[(size_t)c * SP];
    __syncthreads();
    uint4* op = (uint4*)(xcl + ((size_t)n * SP + base) * 32);
#pragma unroll
    for (int r = 0; r < 4; ++r) {
        int idx = r * 256 + tid;
        int px = idx >> 2, q = idx & 3;
        uint4 o;
        o.x = pack2(ld[q * 8 + 0][px], ld[q * 8 + 1][px]);
        o.y = pack2(ld[q * 8 + 2][px], ld[q * 8 + 3][px]);
        o.z = pack2(ld[q * 8 + 4][px], ld[q * 8 + 5][px]);
        o.w = pack2(ld[q * 8 + 6][px], ld[q * 8 + 7][px]);
        op[idx] = o;
    }
}

// ----------------------------------------------------------- MFMA conv ----
// Input bf16 channel-last [n][zyx][CI]. Block (512 thr): (n,z,yt,xt) ->
// 64co x 16y x 16x. Wave (yh 0..1, cq 0..3): 8 y-rows x 16 co. Linear LDS
// staging via global_load_lds. XCD-chunked blockIdx swizzle (T1).
// Output: bf16 channel-last [n][zyx][64]. Stats partials -> part[n][s][co][2048].
template <int CI, int PCH>
__global__ __launch_bounds__(512, 4) void conv5_mfma(const unsigned short* __restrict__ xin,
                                                     const unsigned short* __restrict__ wbuf,
                                                     unsigned short* __restrict__ outp,
                                                     float* __restrict__ part,
                                                     const void* __restrict__ zbuf) {
    constexpr int NCH = CI / 32;
    constexpr int NS  = 5 * NCH;
    __shared__ __align__(16) unsigned short lds[2][12800];   // 2 x 25.6 KB

    const int bid = blockIdx.x;
    const int b   = (bid & 7) * 256 + (bid >> 3);   // XCD-chunked swizzle (2048 = 8*256)
    const int xt  = b & 3;
    const int yt  = (b >> 2) & 3;
    const int z   = (b >> 4) & 63;
    const int n   = b >> 10;
    const int tid = threadIdx.x;
    const int lane = tid & 63, wv = tid >> 6;
    const int xl = lane & 15, kh = lane >> 4;
    const int yh = wv >> 2, cq = wv & 3;

    f32x4 acc[8];
#pragma unroll
    for (int pt = 0; pt < 8; ++pt)
#pragma unroll
        for (int j = 0; j < 4; ++j) acc[pt][j] = 0.f;

    // staging geometry: LDS slot idx = tid + r*512 (linear dest, 16B each)
    long goff[4]; int gval[4];
#pragma unroll
    for (int r = 0; r < 4; ++r) {
        int idx = tid + r * 512;
        int p = idx >> 2, khs = idx & 3;
        int xx = p % 20, yy = p / 20;
        int yi = yt * 16 - 2 + yy, xi = xt * 16 - 2 + xx;
        gval[r] = ((unsigned)yi < 64u) && ((unsigned)xi < 64u);
        goff[r] = ((long)(yi * 64 + xi) * CI + khs * 8) * 2;
    }

    auto stage = [&](int s, int buf) {
        int dz = s / NCH, cich = s % NCH;
        int zi = z + dz - 2;
        bool zok = (unsigned)zi < 64u;
        const char* pb = (const char*)xin
                       + ((size_t)(n * SP + zi * 4096) * CI + cich * 32) * 2;
        char* lb = (char*)&lds[buf][0];
#pragma unroll
        for (int r = 0; r < 4; ++r) {
            int idx = tid + r * 512;
            if (idx < 1600) {
                const void* g = (zok && gval[r]) ? (const void*)(pb + goff[r]) : zbuf;
                gload_lds16(g, lb + idx * 16);
            }
        }
    };

    auto compute = [&](int s, int buf) {
        int dz = s / NCH, cich = s % NCH;
        const unsigned short* wp = wbuf
            + ((size_t)((n * 5 + dz) * NCH + cich) * 25) * 2048
            + cq * 512 + xl * 32 + kh * 8;
        const char* src = (const char*)&lds[buf][0];
        __builtin_amdgcn_s_setprio(1);
#pragma unroll 1
        for (int dx = 0; dx < 5; ++dx) {
            int xx = xl + dx;
            s16x8 fr[12];
#pragma unroll
            for (int r = 0; r < 12; ++r) {
                int row = yh * 8 + r;
                fr[r] = *(const s16x8*)(src + (size_t)(row * 20 + xx) * 64 + kh * 16);
            }
#pragma unroll
            for (int dy = 0; dy < 5; ++dy) {
                s16x8 a = *(const s16x8*)(wp + (size_t)(dy * 5 + dx) * 2048);
#pragma unroll
                for (int pt = 0; pt < 8; ++pt)
                    acc[pt] = __builtin_amdgcn_mfma_f32_16x16x32_bf16(
                        a, fr[pt + dy], acc[pt], 0, 0, 0);
            }
        }
        __builtin_amdgcn_s_setprio(0);
    };

    stage(0, 0);
    __syncthreads();
#pragma unroll 1
    for (int s = 0; s < NS; ++s) {
        if (s + 1 < NS) stage(s + 1, (s + 1) & 1);
        compute(s, s & 1);
        __syncthreads();
    }

    // ---- fused instance-norm partial sums -> part[n][s][co][PCH] ----
    {
        float s1[4], s2[4];
#pragma unroll
        for (int j = 0; j < 4; ++j) { s1[j] = 0.f; s2[j] = 0.f; }
#pragma unroll
        for (int pt = 0; pt < 8; ++pt)
#pragma unroll
            for (int j = 0; j < 4; ++j) {
                float v = acc[pt][j];
                s1[j] += v; s2[j] += v * v;
            }
#pragma unroll
        for (int o = 1; o < 16; o <<= 1)
#pragma unroll
            for (int j = 0; j < 4; ++j) {
                s1[j] += __shfl_xor(s1[j], o, 64);
                s2[j] += __shfl_xor(s2[j], o, 64);
            }
        if (xl == 0) {
            int co = cq * 16 + kh * 4;
            int cb = (b & 1023) * 2 + yh;
#pragma unroll
            for (int j = 0; j < 4; ++j) {
                part[((size_t)(n * 2 + 0) * 64 + co + j) * PCH + cb] = s1[j];
                part[((size_t)(n * 2 + 1) * 64 + co + j) * PCH + cb] = s2[j];
            }
        }
    }

    // ---- bf16 channel-last output via XOR-swizzled LDS transpose ----
    {
        char* tb = (char*)&lds[0][0];     // 32 KB
#pragma unroll
        for (int pt = 0; pt < 8; ++pt) {
            int pix = (yh * 8 + pt) * 16 + xl;
            unsigned int ad = ((unsigned)(pix * 128 + cq * 32 + kh * 8))
                              ^ ((unsigned)(pix & 7) << 4);
            *(unsigned int*)(tb + ad)     = pack2(acc[pt][0], acc[pt][1]);
            *(unsigned int*)(tb + ad + 4) = pack2(acc[pt][2], acc[pt][3]);
        }
        __syncthreads();
#pragma unroll
        for (int it = 0; it < 4; ++it) {
            int idx = it * 512 + tid;
            int pix = idx >> 3, ch = idx & 7;
            uint4 v = *(const uint4*)(tb + (((unsigned)idx * 16)
                                            ^ ((unsigned)(pix & 7) << 4)));
            int y = yt * 16 + (pix >> 4), x = xt * 16 + (pix & 15);
            *(uint4*)(outp
                      + ((size_t)(n * SP + z * 4096 + y * 64 + x) * 64 + ch * 8)) = v;
        }
    }
}

// ------------------------------------------------- stats finalize ---------
template <int CH>
__global__ void stats_fin(const float* __restrict__ part, float* __restrict__ st,
                          float invS) {
    int blk = blockIdx.x;
    int n = blk >> 6, co = blk & 63;
    int tid = threadIdx.x;
    const float* ps = part + ((size_t)(n * 2 + 0) * 64 + co) * CH;
    const float* pq = part + ((size_t)(n * 2 + 1) * 64 + co) * CH;
    float s1 = 0.f, s2 = 0.f;
    for (int i = tid; i < CH; i += 256) { s1 += ps[i]; s2 += pq[i]; }
#pragma unroll
    for (int o = 1; o < 64; o <<= 1) {
        s1 += __shfl_xor(s1, o, 64);
        s2 += __shfl_xor(s2, o, 64);
    }
    __shared__ float sh1[4], sh2[4];
    if ((tid & 63) == 0) { sh1[tid >> 6] = s1; sh2[tid >> 6] = s2; }
    __syncthreads();
    if (tid == 0) {
        float a = sh1[0] + sh1[1] + sh1[2] + sh1[3];
        float q = sh2[0] + sh2[1] + sh2[2] + sh2[3];
        float mean = a * invS;
        float var  = q * invS - mean * mean;
        st[(n * 64 + co) * 2]     = mean;
        st[(n * 64 + co) * 2 + 1] = rsqrtf(var + 1e-5f);
    }
}

// -------------------------------------- norm+mish in-place, channel-last --
__global__ void norm_mish_cl_kernel(unsigned short* __restrict__ h,
                                    const float* __restrict__ st,
                                    const float* __restrict__ gamma,
                                    const float* __restrict__ beta) {
    size_t idx = (size_t)blockIdx.x * 256 + threadIdx.x;   // NB*SP*8 items
    uint4 v = ((uint4*)h)[idx];
    int c0 = ((int)(idx & 7)) * 8;
    size_t pix = idx >> 3;
    int n = (int)(pix >> 18);
    unsigned int* pv = &v.x;
#pragma unroll
    for (int q = 0; q < 4; ++q) {
        unsigned int wv = pv[q];
        unsigned int out = 0;
#pragma unroll
        for (int hv = 0; hv < 2; ++hv) {
            int c = c0 + 2 * q + hv;
            int nc = n * 64 + c;
            float val = bf2f((unsigned short)((wv >> (16 * hv)) & 0xffffu));
            float xh = (val - st[nc * 2]) * st[nc * 2 + 1] * gamma[c] + beta[c];
            out |= ((unsigned int)f2bf(mish_f(xh))) << (16 * hv);
        }
        pv[q] = out;
    }
    ((uint4*)h)[idx] = v;
}

// ----------------------------------------------------------- norm+mish ----
template <int SHIFT>
__global__ void norm_mish_kernel(float* __restrict__ buf, const float* __restrict__ stats,
                                 const float* __restrict__ gamma, const float* __restrict__ beta,
                                 int total4) {
    int idx = blockIdx.x * 256 + threadIdx.x;
    if (idx >= total4) return;
    float4 v = reinterpret_cast<float4*>(buf)[idx];
    int nc = idx >> (SHIFT - 2);
    int c  = nc & 63;
    float mean = stats[nc * 2], inv = stats[nc * 2 + 1];
    float ga = gamma[c], be = beta[c];
    float* pv = &v.x;
#pragma unroll
    for (int k = 0; k < 4; ++k) {
        float xh = (pv[k] - mean) * inv * ga + be;
        pv[k] = mish_f(xh);
    }
    reinterpret_cast<float4*>(buf)[idx] = v;
}

// ----------------------------------------------------------- down conv ----
// Reads RAW conv2 output (bf16 CL h3), applies norm+mish (st2), writes the
// normalized f32 NCDHW xskip output, does 2x2x2 stride-2 conv, writes raw y
// + y-stats partials [n][s][co][256].
__global__ __launch_bounds__(256) void down_conv_kernel(const unsigned short* __restrict__ h3,
                                                        const float* __restrict__ dw,
                                                        const float* __restrict__ st,
                                                        const float* __restrict__ gamma,
                                                        const float* __restrict__ beta,
                                                        float* __restrict__ xskip,
                                                        float* __restrict__ out,
                                                        float* __restrict__ part) {
    __shared__ float ls[8][2][8][64];
    int b   = blockIdx.x;
    int yt  = b & 7;
    int z   = (b >> 3) & 31;
    int n   = b >> 8;
    int tid = threadIdx.x;
    int xo  = tid & 31;
    int cog = tid >> 5;

    float acc[4][8];
#pragma unroll
    for (int yo = 0; yo < 4; ++yo)
#pragma unroll
        for (int j = 0; j < 8; ++j) acc[yo][j] = 0.f;

    for (int cc = 0; cc < 8; ++cc) {
        // stage + normalize + write xskip: 1024 pixels, 4 per thread
#pragma unroll
        for (int r = 0; r < 4; ++r) {
            int p  = r * 256 + tid;       // 0..1023
            int xx = p & 63, yy = (p >> 6) & 7, dz = p >> 9;
            int zi = 2 * z + dz, yi = yt * 8 + yy;
            size_t pix = (size_t)n * SP + (size_t)zi * 4096 + yi * 64 + xx;
            uint4 v = *(const uint4*)(h3 + pix * 64 + cc * 8);
            unsigned int* pv = &v.x;
#pragma unroll
            for (int q = 0; q < 4; ++q) {
#pragma unroll
                for (int hv = 0; hv < 2; ++hv) {
                    int c  = 2 * q + hv;
                    int ci = cc * 8 + c;
                    int nc = n * 64 + ci;
                    float val = bf2f((unsigned short)((pv[q] >> (16 * hv)) & 0xffffu));
                    float nv  = mish_f((val - st[nc * 2]) * st[nc * 2 + 1] * gamma[ci]
                                       + beta[ci]);
                    ls[c][dz][yy][xx] = nv;
                    xskip[((size_t)(n * CO + ci) * 64 + zi) * 4096 + yi * 64 + xx] = nv;
                }
            }
        }
        __syncthreads();
#pragma unroll 1
        for (int c = 0; c < 8; ++c) {
            int ci = cc * 8 + c;
#pragma unroll
            for (int tap = 0; tap < 8; ++tap) {
                int dz = tap >> 2, dy = (tap >> 1) & 1, dx = tap & 1;
                float w[8];
#pragma unroll
                for (int j = 0; j < 8; ++j)
                    w[j] = dw[((size_t)(cog * 8 + j) * CO + ci) * 8 + tap];
#pragma unroll
                for (int yo = 0; yo < 4; ++yo) {
                    float xv = ls[c][dz][yo * 2 + dy][2 * xo + dx];
#pragma unroll
                    for (int j = 0; j < 8; ++j) acc[yo][j] += w[j] * xv;
                }
            }
        }
        __syncthreads();
    }
#pragma unroll
    for (int yo = 0; yo < 4; ++yo)
#pragma unroll
        for (int j = 0; j < 8; ++j)
            out[((size_t)(n * CO + cog * 8 + j) * 32 + z) * 1024 + (yt * 4 + yo) * 32 + xo]
                = acc[yo][j];

    // y-stats partials
    float s1[8], s2[8];
#pragma unroll
    for (int j = 0; j < 8; ++j) { s1[j] = 0.f; s2[j] = 0.f; }
#pragma unroll
    for (int yo = 0; yo < 4; ++yo)
#pragma unroll
        for (int j = 0; j < 8; ++j) {
            float v = acc[yo][j];
            s1[j] += v; s2[j] += v * v;
        }
#pragma unroll
    for (int o = 1; o < 32; o <<= 1)
#pragma unroll
        for (int j = 0; j < 8; ++j) {
            s1[j] += __shfl_xor(s1[j], o, 64);
            s2[j] += __shfl_xor(s2[j], o, 64);
        }
    if (xo == 0) {
        int cb = b & 255;
#pragma unroll
        for (int j = 0; j < 8; ++j) {
            int co = cog * 8 + j;
            part[((size_t)(n * 2 + 0) * 64 + co) * 256 + cb] = s1[j];
            part[((size_t)(n * 2 + 1) * 64 + co) * 256 + cb] = s2[j];
        }
    }
}

// -------------------------------------------------------------- launch ----
extern "C" void kernel_launch(void* const* d_in, const int* in_sizes, int n_in,
                              void* d_out, int out_size, void* d_ws, size_t ws_size,
                              hipStream_t stream) {
    const float* x      = (const float*)d_in[0];
    const float* t      = (const float*)d_in[1];
    const float* l1_c5  = (const float*)d_in[2];
    const float* l1_c3  = (const float*)d_in[3];
    const float* l1_c1  = (const float*)d_in[4];
    const float* l1_a3  = (const float*)d_in[5];
    const float* l1_a5  = (const float*)d_in[6];
    const float* l1_gw  = (const float*)d_in[7];
    const float* l1_gb  = (const float*)d_in[8];
    const float* l1_ga  = (const float*)d_in[9];
    const float* l1_be  = (const float*)d_in[10];
    const float* l2_c5  = (const float*)d_in[11];
    const float* l2_c3  = (const float*)d_in[12];
    const float* l2_c1  = (const float*)d_in[13];
    const float* l2_a3  = (const float*)d_in[14];
    const float* l2_a5  = (const float*)d_in[15];
    const float* l2_gw  = (const float*)d_in[16];
    const float* l2_gb  = (const float*)d_in[17];
    const float* l2_ga  = (const float*)d_in[18];
    const float* l2_be  = (const float*)d_in[19];
    const float* down_w = (const float*)d_in[20];
    const float* dn_ga  = (const float*)d_in[21];
    const float* dn_be  = (const float*)d_in[22];

    char* ws = (char*)d_ws;
    // Lifetime-overlapped layout (≤ 139.7 MB, under R0's proven 140.4):
    // [0, 67.1M):   xcl (33.5M, phase 1) then h3 (67.1M, conv2 output)
    // part1 (2M) lives at 33.5M inside the h3 region — dead before conv2 runs.
    unsigned short* xcl = (unsigned short*)(ws);                  // 33,554,432 B
    unsigned short* h3  = (unsigned short*)(ws);                  // 67,108,864 B (after conv1)
    float* part1 = (float*)(ws + 33554432);                       //  2,097,152 B (transient)
    unsigned short* h2  = (unsigned short*)(ws + 67108864);       // 67,108,864 B
    unsigned short* w1  = (unsigned short*)(ws + 134217728);      //  1,024,000 B
    unsigned short* w2  = (unsigned short*)(ws + 135241728);      //  2,048,000 B
    float* part2 = (float*)(ws + 137289728);                      //  2,097,152 B
    float* part3 = (float*)(ws + 139386880);                      //    262,144 B
    float* g1    = (float*)(ws + 139649024);                      //      2,560 B
    float* g2    = (float*)(ws + 139651584);                      //      2,560 B
    float* st1   = (float*)(ws + 139654144);                      //      1,024 B
    float* st2   = (float*)(ws + 139655168);                      //      1,024 B
    float* st3   = (float*)(ws + 139656192);                      //      1,024 B
    float* zbuf  = (float*)(ws + 139657216);                      //        256 B

    float* yout  = (float*)d_out;
    float* xskip = (float*)d_out + Y_SZ;

    gate2_kernel<<<1, 256, 0, stream>>>(t, l1_gw, l1_gb, g1, l2_gw, l2_gb, g2, zbuf);
    synth2_kernel<<<6000, 256, 0, stream>>>(g1, l1_c5, l1_c3, l1_c1, l1_a3, l1_a5, w1,
                                            g2, l2_c5, l2_c3, l2_c1, l2_a3, l2_a5, w2);
    x_to_cl<<<2048, 256, 0, stream>>>(x, xcl);

    // layer 1: conv (bf16 CL in -> bf16 CL raw h2) + fused stats partials
    conv5_mfma<32, 2048><<<2048, 512, 0, stream>>>(xcl, w1, h2, part1, zbuf);
    stats_fin<2048><<<128, 256, 0, stream>>>(part1, st1, 1.f / SP);
    norm_mish_cl_kernel<<<16384, 256, 0, stream>>>(h2, st1, l1_ga, l1_be);

    // layer 2: conv (bf16 CL in -> bf16 CL raw h3, overwrites xcl) + partials
    conv5_mfma<64, 2048><<<2048, 512, 0, stream>>>(h2, w2, h3, part2, zbuf);
    stats_fin<2048><<<128, 256, 0, stream>>>(part2, st2, 1.f / SP);

    // downsample: norm+mish(h3) -> writes f32 xskip + conv -> raw y + partials
    down_conv_kernel<<<NB * 32 * 8, 256, 0, stream>>>(h3, down_w, st2, l2_ga, l2_be,
                                                      xskip, yout, part3);
    stats_fin<256><<<128, 256, 0, stream>>>(part3, st3, 1.f / 32768.f);
    norm_mish_kernel<15><<<(NC * 32768 / 4 + 255) / 256, 256, 0, stream>>>(
        yout, st3, dn_ga, dn_be, NC * 32768 / 4);
}

// Round 13
// 758.431 us; speedup vs baseline: 4.3731x; 1.0532x over previous
//
#include <hip/hip_runtime.h>
#include <cstdint>
#include <cstddef>

constexpr int NB  = 2;
constexpr int CO  = 64;
constexpr int DIM = 64;
constexpr int SP  = DIM * DIM * DIM;       // 262144
constexpr int NC  = NB * CO;               // 128
constexpr int Y_SZ = NB * CO * 32 * 32 * 32;

typedef float f32x4 __attribute__((ext_vector_type(4)));
typedef short s16x8 __attribute__((ext_vector_type(8)));

__device__ __forceinline__ unsigned short f2bf(float f) {
    unsigned int u = __float_as_uint(f);
    unsigned int r = (u + 0x7fffu + ((u >> 16) & 1u)) >> 16;
    return (unsigned short)r;
}
__device__ __forceinline__ float bf2f(unsigned short u) {
    return __uint_as_float((unsigned int)u << 16);
}
__device__ __forceinline__ unsigned int pack2(float a, float b) {
    return (unsigned int)f2bf(a) | ((unsigned int)f2bf(b) << 16);
}
// mish(x) = x * tanh(softplus(x)) = x*(e^2+2e)/(e^2+2e+2), e = exp(x)
__device__ __forceinline__ float mish_f(float x) {
    float e = __expf(x);
    float num = e * (e + 2.f);
    float r = x * num * __builtin_amdgcn_rcpf(num + 2.f);
    return (x > 15.f) ? x : r;
}

__device__ __forceinline__ void gload_lds16(const void* g, void* l) {
    __builtin_amdgcn_global_load_lds(
        (const __attribute__((address_space(1))) unsigned int*)g,
        (__attribute__((address_space(3))) unsigned int*)l, 16, 0, 0);
}

// ------------------------------------------------ gate both layers + zero --
__global__ void gate2_kernel(const float* __restrict__ t,
                             const float* __restrict__ gw1, const float* __restrict__ gb1,
                             float* __restrict__ g1,
                             const float* __restrict__ gw2, const float* __restrict__ gb2,
                             float* __restrict__ g2,
                             float* __restrict__ zbuf) {
    int tid = threadIdx.x;                 // 0..255
    if (tid < 64) zbuf[tid] = 0.f;
    int layer = tid >> 7;                  // 0: layer1, 1: layer2
    int lt = tid & 127;
    int n = lt >> 6, co = lt & 63;
    const float* gw = layer ? gw2 : gw1;
    const float* gb = layer ? gb2 : gb1;
    float* g = layer ? g2 : g1;
    float tl[10];
#pragma unroll
    for (int k = 0; k < 10; ++k) tl[k] = t[n * 10 + k];
    float l[5];
#pragma unroll
    for (int e = 0; e < 5; ++e) {
        int row = e * CO + co;
        float acc = gb[row];
#pragma unroll
        for (int k = 0; k < 10; ++k) acc += tl[k] * gw[row * 10 + k];
        l[e] = acc;
    }
    float m = l[0];
#pragma unroll
    for (int e = 1; e < 5; ++e) m = fmaxf(m, l[e]);
    float s = 0.f;
#pragma unroll
    for (int e = 0; e < 5; ++e) { l[e] = expf(l[e] - m); s += l[e]; }
    float inv = 1.f / s;
#pragma unroll
    for (int e = 0; e < 5; ++e) g[(n * 5 + e) * CO + co] = l[e] * inv;
}

// --------------------------------------------------------------- synth ----
// wbuf (bf16): [n][dz(5)][cich(CI/32)][t(25)][co(64)][cil(32)]
template <int CI>
__device__ __forceinline__ void synth_one(int idx, const float* __restrict__ g,
                                          const float* __restrict__ c5, const float* __restrict__ c3,
                                          const float* __restrict__ c1, const float* __restrict__ a3,
                                          const float* __restrict__ a5,
                                          unsigned short* __restrict__ wbuf) {
    int tap = idx % 125;
    int ci  = (idx / 125) % CI;
    int co  = (idx / (125 * CI)) % CO;
    int n   = idx / (125 * CI * CO);
    const float* gn = g + n * 5 * CO;
    float g0 = gn[0 * CO + co], g1 = gn[1 * CO + co], g2 = gn[2 * CO + co],
          g3 = gn[3 * CO + co], g4 = gn[4 * CO + co];
    int dz = tap / 25, dy = (tap / 5) % 5, dx = tap % 5;
    int oc = co * CI + ci;
    float v = g0 * c5[(size_t)oc * 125 + tap] + g4 * a5[oc] * (1.f / 125.f);
    if (dz >= 1 && dz <= 3 && dy >= 1 && dy <= 3 && dx >= 1 && dx <= 3)
        v += g1 * c3[(size_t)oc * 27 + (dz - 1) * 9 + (dy - 1) * 3 + (dx - 1)]
           + g3 * a3[oc] * (1.f / 27.f);
    if (dz == 2 && dy == 2 && dx == 2) v += g2 * c1[oc];
    int t = (dy * 5 + dx);
    int cich = ci >> 5, cil = ci & 31;
    wbuf[((((size_t)(n * 5 + dz) * (CI / 32) + cich) * 25 + t) * 64 + co) * 32 + cil] = f2bf(v);
}

__global__ void synth2_kernel(const float* __restrict__ g1,
                              const float* __restrict__ c51, const float* __restrict__ c31,
                              const float* __restrict__ c11, const float* __restrict__ a31,
                              const float* __restrict__ a51, unsigned short* __restrict__ w1,
                              const float* __restrict__ g2,
                              const float* __restrict__ c52, const float* __restrict__ c32,
                              const float* __restrict__ c12, const float* __restrict__ a32,
                              const float* __restrict__ a52, unsigned short* __restrict__ w2) {
    constexpr int T1 = NB * CO * 32 * 125;   // 512,000
    constexpr int T2 = NB * CO * 64 * 125;   // 1,024,000
    int idx = blockIdx.x * 256 + threadIdx.x;
    if (idx < T1)
        synth_one<32>(idx, g1, c51, c31, c11, a31, a51, w1);
    else if (idx < T1 + T2)
        synth_one<64>(idx - T1, g2, c52, c32, c12, a32, a52, w2);
}

// -------------------------------------------------------------- x->CL -----
__global__ __launch_bounds__(256) void x_to_cl(const float* __restrict__ x,
                                               unsigned short* __restrict__ xcl) {
    __shared__ float ld[32][256];
    int b = blockIdx.x;                   // 2048 = n(2) x 1024
    int n = b >> 10;
    size_t base = (size_t)(b & 1023) * 256;
    int tid = threadIdx.x;
    const float* xp = x + (size_t)n * 32 * SP + base + tid;
#pragma unroll
    for (int c = 0; c < 32; ++c) ld[c][tid] = xp[(size_t)c * SP];
    __syncthreads();
    uint4* op = (uint4*)(xcl + ((size_t)n * SP + base) * 32);
#pragma unroll
    for (int r = 0; r < 4; ++r) {
        int idx = r * 256 + tid;
        int px = idx >> 2, q = idx & 3;
        uint4 o;
        o.x = pack2(ld[q * 8 + 0][px], ld[q * 8 + 1][px]);
        o.y = pack2(ld[q * 8 + 2][px], ld[q * 8 + 3][px]);
        o.z = pack2(ld[q * 8 + 4][px], ld[q * 8 + 5][px]);
        o.w = pack2(ld[q * 8 + 6][px], ld[q * 8 + 7][px]);
        op[idx] = o;
    }
}

// ----------------------------------------------------------- MFMA conv ----
// Input bf16 channel-last [n][zyx][CI]. Block (512 thr): (n,z,yt,xt) ->
// 64co x 16y x 16x. Wave (yh 0..1, cq 0..3): 8 y-rows x 16 co. Linear LDS
// staging via global_load_lds. XCD-chunked blockIdx swizzle (T1).
// Output: OUT_G8 ? grouped-8 CL [n][cg(8)][zyx][8] : CL-64 [n][zyx][64].
template <int CI, int PCH, bool OUT_G8>
__global__ __launch_bounds__(512, 4) void conv5_mfma(const unsigned short* __restrict__ xin,
                                                     const unsigned short* __restrict__ wbuf,
                                                     unsigned short* __restrict__ outp,
                                                     float* __restrict__ part,
                                                     const void* __restrict__ zbuf) {
    constexpr int NCH = CI / 32;
    constexpr int NS  = 5 * NCH;
    __shared__ __align__(16) unsigned short lds[2][12800];   // 2 x 25.6 KB

    const int bid = blockIdx.x;
    const int b   = (bid & 7) * 256 + (bid >> 3);   // XCD-chunked swizzle (2048 = 8*256)
    const int xt  = b & 3;
    const int yt  = (b >> 2) & 3;
    const int z   = (b >> 4) & 63;
    const int n   = b >> 10;
    const int tid = threadIdx.x;
    const int lane = tid & 63, wv = tid >> 6;
    const int xl = lane & 15, kh = lane >> 4;
    const int yh = wv >> 2, cq = wv & 3;

    f32x4 acc[8];
#pragma unroll
    for (int pt = 0; pt < 8; ++pt)
#pragma unroll
        for (int j = 0; j < 4; ++j) acc[pt][j] = 0.f;

    // staging geometry: LDS slot idx = tid + r*512 (linear dest, 16B each)
    long goff[4]; int gval[4];
#pragma unroll
    for (int r = 0; r < 4; ++r) {
        int idx = tid + r * 512;
        int p = idx >> 2, khs = idx & 3;
        int xx = p % 20, yy = p / 20;
        int yi = yt * 16 - 2 + yy, xi = xt * 16 - 2 + xx;
        gval[r] = ((unsigned)yi < 64u) && ((unsigned)xi < 64u);
        goff[r] = ((long)(yi * 64 + xi) * CI + khs * 8) * 2;
    }

    auto stage = [&](int s, int buf) {
        int dz = s / NCH, cich = s % NCH;
        int zi = z + dz - 2;
        bool zok = (unsigned)zi < 64u;
        const char* pb = (const char*)xin
                       + ((size_t)(n * SP + zi * 4096) * CI + cich * 32) * 2;
        char* lb = (char*)&lds[buf][0];
#pragma unroll
        for (int r = 0; r < 4; ++r) {
            int idx = tid + r * 512;
            if (idx < 1600) {
                const void* g = (zok && gval[r]) ? (const void*)(pb + goff[r]) : zbuf;
                gload_lds16(g, lb + idx * 16);
            }
        }
    };

    auto compute = [&](int s, int buf) {
        int dz = s / NCH, cich = s % NCH;
        const unsigned short* wp = wbuf
            + ((size_t)((n * 5 + dz) * NCH + cich) * 25) * 2048
            + cq * 512 + xl * 32 + kh * 8;
        const char* src = (const char*)&lds[buf][0];
        __builtin_amdgcn_s_setprio(1);
#pragma unroll 1
        for (int dx = 0; dx < 5; ++dx) {
            int xx = xl + dx;
            s16x8 fr[12];
#pragma unroll
            for (int r = 0; r < 12; ++r) {
                int row = yh * 8 + r;
                fr[r] = *(const s16x8*)(src + (size_t)(row * 20 + xx) * 64 + kh * 16);
            }
#pragma unroll
            for (int dy = 0; dy < 5; ++dy) {
                s16x8 a = *(const s16x8*)(wp + (size_t)(dy * 5 + dx) * 2048);
#pragma unroll
                for (int pt = 0; pt < 8; ++pt)
                    acc[pt] = __builtin_amdgcn_mfma_f32_16x16x32_bf16(
                        a, fr[pt + dy], acc[pt], 0, 0, 0);
            }
        }
        __builtin_amdgcn_s_setprio(0);
    };

    stage(0, 0);
    __syncthreads();
#pragma unroll 1
    for (int s = 0; s < NS; ++s) {
        if (s + 1 < NS) stage(s + 1, (s + 1) & 1);
        compute(s, s & 1);
        __syncthreads();
    }

    // ---- fused instance-norm partial sums -> part[n][s][co][PCH] ----
    {
        float s1[4], s2[4];
#pragma unroll
        for (int j = 0; j < 4; ++j) { s1[j] = 0.f; s2[j] = 0.f; }
#pragma unroll
        for (int pt = 0; pt < 8; ++pt)
#pragma unroll
            for (int j = 0; j < 4; ++j) {
                float v = acc[pt][j];
                s1[j] += v; s2[j] += v * v;
            }
#pragma unroll
        for (int o = 1; o < 16; o <<= 1)
#pragma unroll
            for (int j = 0; j < 4; ++j) {
                s1[j] += __shfl_xor(s1[j], o, 64);
                s2[j] += __shfl_xor(s2[j], o, 64);
            }
        if (xl == 0) {
            int co = cq * 16 + kh * 4;
            int cb = (b & 1023) * 2 + yh;
#pragma unroll
            for (int j = 0; j < 4; ++j) {
                part[((size_t)(n * 2 + 0) * 64 + co + j) * PCH + cb] = s1[j];
                part[((size_t)(n * 2 + 1) * 64 + co + j) * PCH + cb] = s2[j];
            }
        }
    }

    // ---- bf16 output via XOR-swizzled LDS transpose ----
    {
        char* tb = (char*)&lds[0][0];     // 32 KB
#pragma unroll
        for (int pt = 0; pt < 8; ++pt) {
            int pix = (yh * 8 + pt) * 16 + xl;
            unsigned int ad = ((unsigned)(pix * 128 + cq * 32 + kh * 8))
                              ^ ((unsigned)(pix & 7) << 4);
            *(unsigned int*)(tb + ad)     = pack2(acc[pt][0], acc[pt][1]);
            *(unsigned int*)(tb + ad + 4) = pack2(acc[pt][2], acc[pt][3]);
        }
        __syncthreads();
#pragma unroll
        for (int it = 0; it < 4; ++it) {
            int idx = it * 512 + tid;
            int pix = idx >> 3, ch = idx & 7;
            uint4 v = *(const uint4*)(tb + (((unsigned)idx * 16)
                                            ^ ((unsigned)(pix & 7) << 4)));
            int y = yt * 16 + (pix >> 4), x = xt * 16 + (pix & 15);
            size_t zyx = (size_t)z * 4096 + y * 64 + x;
            if (OUT_G8)
                *(uint4*)(outp + ((size_t)(n * 8 + ch) * SP + zyx) * 8) = v;
            else
                *(uint4*)(outp + ((size_t)n * SP + zyx) * 64 + ch * 8) = v;
        }
    }
}

// ------------------------------------------------- stats finalize ---------
template <int CH>
__global__ void stats_fin(const float* __restrict__ part, float* __restrict__ st,
                          float invS) {
    int blk = blockIdx.x;
    int n = blk >> 6, co = blk & 63;
    int tid = threadIdx.x;
    const float* ps = part + ((size_t)(n * 2 + 0) * 64 + co) * CH;
    const float* pq = part + ((size_t)(n * 2 + 1) * 64 + co) * CH;
    float s1 = 0.f, s2 = 0.f;
    for (int i = tid; i < CH; i += 256) { s1 += ps[i]; s2 += pq[i]; }
#pragma unroll
    for (int o = 1; o < 64; o <<= 1) {
        s1 += __shfl_xor(s1, o, 64);
        s2 += __shfl_xor(s2, o, 64);
    }
    __shared__ float sh1[4], sh2[4];
    if ((tid & 63) == 0) { sh1[tid >> 6] = s1; sh2[tid >> 6] = s2; }
    __syncthreads();
    if (tid == 0) {
        float a = sh1[0] + sh1[1] + sh1[2] + sh1[3];
        float q = sh2[0] + sh2[1] + sh2[2] + sh2[3];
        float mean = a * invS;
        float var  = q * invS - mean * mean;
        st[(n * 64 + co) * 2]     = mean;
        st[(n * 64 + co) * 2 + 1] = rsqrtf(var + 1e-5f);
    }
}

// -------------------------------------- norm+mish in-place, channel-last --
__global__ void norm_mish_cl_kernel(unsigned short* __restrict__ h,
                                    const float* __restrict__ st,
                                    const float* __restrict__ gamma,
                                    const float* __restrict__ beta) {
    size_t idx = (size_t)blockIdx.x * 256 + threadIdx.x;   // NB*SP*8 items
    uint4 v = ((uint4*)h)[idx];
    int c0 = ((int)(idx & 7)) * 8;
    size_t pix = idx >> 3;
    int n = (int)(pix >> 18);
    unsigned int* pv = &v.x;
#pragma unroll
    for (int q = 0; q < 4; ++q) {
        unsigned int wv = pv[q];
        unsigned int out = 0;
#pragma unroll
        for (int hv = 0; hv < 2; ++hv) {
            int c = c0 + 2 * q + hv;
            int nc = n * 64 + c;
            float val = bf2f((unsigned short)((wv >> (16 * hv)) & 0xffffu));
            float xh = (val - st[nc * 2]) * st[nc * 2 + 1] * gamma[c] + beta[c];
            out |= ((unsigned int)f2bf(mish_f(xh))) << (16 * hv);
        }
        pv[q] = out;
    }
    ((uint4*)h)[idx] = v;
}

// ----------------------------------------------------------- norm+mish ----
template <int SHIFT>
__global__ void norm_mish_kernel(float* __restrict__ buf, const float* __restrict__ stats,
                                 const float* __restrict__ gamma, const float* __restrict__ beta,
                                 int total4) {
    int idx = blockIdx.x * 256 + threadIdx.x;
    if (idx >= total4) return;
    float4 v = reinterpret_cast<float4*>(buf)[idx];
    int nc = idx >> (SHIFT - 2);
    int c  = nc & 63;
    float mean = stats[nc * 2], inv = stats[nc * 2 + 1];
    float ga = gamma[c], be = beta[c];
    float* pv = &v.x;
#pragma unroll
    for (int k = 0; k < 4; ++k) {
        float xh = (pv[k] - mean) * inv * ga + be;
        pv[k] = mish_f(xh);
    }
    reinterpret_cast<float4*>(buf)[idx] = v;
}

// ----------------------------------------------------------- down conv ----
// Reads RAW conv2 output in grouped-8 CL layout h3[(n*8+cg)*SP + zyx][8],
// applies norm+mish (st2), writes normalized f32 NCDHW xskip, does 2x2x2
// stride-2 conv, writes raw y + y-stats partials [n][s][co][256].
__global__ __launch_bounds__(256) void down_conv_kernel(const unsigned short* __restrict__ h3,
                                                        const float* __restrict__ dw,
                                                        const float* __restrict__ st,
                                                        const float* __restrict__ gamma,
                                                        const float* __restrict__ beta,
                                                        float* __restrict__ xskip,
                                                        float* __restrict__ out,
                                                        float* __restrict__ part) {
    __shared__ float ls[8][2][8][64];
    int b   = blockIdx.x;
    int yt  = b & 7;
    int z   = (b >> 3) & 31;
    int n   = b >> 8;
    int tid = threadIdx.x;
    int xo  = tid & 31;
    int cog = tid >> 5;

    float acc[4][8];
#pragma unroll
    for (int yo = 0; yo < 4; ++yo)
#pragma unroll
        for (int j = 0; j < 8; ++j) acc[yo][j] = 0.f;

    for (int cc = 0; cc < 8; ++cc) {
        // stage + normalize + write xskip: 1024 pixels, 4 per thread.
        // h3 grouped-8: consecutive pixels -> consecutive uint4 (coalesced).
#pragma unroll
        for (int r = 0; r < 4; ++r) {
            int p  = r * 256 + tid;       // 0..1023
            int xx = p & 63, yy = (p >> 6) & 7, dz = p >> 9;
            int zi = 2 * z + dz, yi = yt * 8 + yy;
            size_t zyx = (size_t)zi * 4096 + yi * 64 + xx;
            uint4 v = *(const uint4*)(h3 + ((size_t)(n * 8 + cc) * SP + zyx) * 8);
            unsigned int* pv = &v.x;
#pragma unroll
            for (int q = 0; q < 4; ++q) {
#pragma unroll
                for (int hv = 0; hv < 2; ++hv) {
                    int c  = 2 * q + hv;
                    int ci = cc * 8 + c;
                    int nc = n * 64 + ci;
                    float val = bf2f((unsigned short)((pv[q] >> (16 * hv)) & 0xffffu));
                    float nv  = mish_f((val - st[nc * 2]) * st[nc * 2 + 1] * gamma[ci]
                                       + beta[ci]);
                    ls[c][dz][yy][xx] = nv;
                    xskip[((size_t)(n * CO + ci) * 64 + zi) * 4096 + yi * 64 + xx] = nv;
                }
            }
        }
        __syncthreads();
#pragma unroll 1
        for (int c = 0; c < 8; ++c) {
            int ci = cc * 8 + c;
#pragma unroll
            for (int tap = 0; tap < 8; ++tap) {
                int dz = tap >> 2, dy = (tap >> 1) & 1, dx = tap & 1;
                float w[8];
#pragma unroll
                for (int j = 0; j < 8; ++j)
                    w[j] = dw[((size_t)(cog * 8 + j) * CO + ci) * 8 + tap];
#pragma unroll
                for (int yo = 0; yo < 4; ++yo) {
                    float xv = ls[c][dz][yo * 2 + dy][2 * xo + dx];
#pragma unroll
                    for (int j = 0; j < 8; ++j) acc[yo][j] += w[j] * xv;
                }
            }
        }
        __syncthreads();
    }
#pragma unroll
    for (int yo = 0; yo < 4; ++yo)
#pragma unroll
        for (int j = 0; j < 8; ++j)
            out[((size_t)(n * CO + cog * 8 + j) * 32 + z) * 1024 + (yt * 4 + yo) * 32 + xo]
                = acc[yo][j];

    // y-stats partials
    float s1[8], s2[8];
#pragma unroll
    for (int j = 0; j < 8; ++j) { s1[j] = 0.f; s2[j] = 0.f; }
#pragma unroll
    for (int yo = 0; yo < 4; ++yo)
#pragma unroll
        for (int j = 0; j < 8; ++j) {
            float v = acc[yo][j];
            s1[j] += v; s2[j] += v * v;
        }
#pragma unroll
    for (int o = 1; o < 32; o <<= 1)
#pragma unroll
        for (int j = 0; j < 8; ++j) {
            s1[j] += __shfl_xor(s1[j], o, 64);
            s2[j] += __shfl_xor(s2[j], o, 64);
        }
    if (xo == 0) {
        int cb = b & 255;
#pragma unroll
        for (int j = 0; j < 8; ++j) {
            int co = cog * 8 + j;
            part[((size_t)(n * 2 + 0) * 64 + co) * 256 + cb] = s1[j];
            part[((size_t)(n * 2 + 1) * 64 + co) * 256 + cb] = s2[j];
        }
    }
}

// -------------------------------------------------------------- launch ----
extern "C" void kernel_launch(void* const* d_in, const int* in_sizes, int n_in,
                              void* d_out, int out_size, void* d_ws, size_t ws_size,
                              hipStream_t stream) {
    const float* x      = (const float*)d_in[0];
    const float* t      = (const float*)d_in[1];
    const float* l1_c5  = (const float*)d_in[2];
    const float* l1_c3  = (const float*)d_in[3];
    const float* l1_c1  = (const float*)d_in[4];
    const float* l1_a3  = (const float*)d_in[5];
    const float* l1_a5  = (const float*)d_in[6];
    const float* l1_gw  = (const float*)d_in[7];
    const float* l1_gb  = (const float*)d_in[8];
    const float* l1_ga  = (const float*)d_in[9];
    const float* l1_be  = (const float*)d_in[10];
    const float* l2_c5  = (const float*)d_in[11];
    const float* l2_c3  = (const float*)d_in[12];
    const float* l2_c1  = (const float*)d_in[13];
    const float* l2_a3  = (const float*)d_in[14];
    const float* l2_a5  = (const float*)d_in[15];
    const float* l2_gw  = (const float*)d_in[16];
    const float* l2_gb  = (const float*)d_in[17];
    const float* l2_ga  = (const float*)d_in[18];
    const float* l2_be  = (const float*)d_in[19];
    const float* down_w = (const float*)d_in[20];
    const float* dn_ga  = (const float*)d_in[21];
    const float* dn_be  = (const float*)d_in[22];

    char* ws = (char*)d_ws;
    // Lifetime-overlapped layout (≤ 139.7 MB):
    // [0, 67.1M):   xcl (33.5M, phase 1) then h3 (67.1M, conv2 output)
    // part1 (2M) lives at 33.5M inside the h3 region — dead before conv2 runs.
    unsigned short* xcl = (unsigned short*)(ws);                  // 33,554,432 B
    unsigned short* h3  = (unsigned short*)(ws);                  // 67,108,864 B (after conv1)
    float* part1 = (float*)(ws + 33554432);                       //  2,097,152 B (transient)
    unsigned short* h2  = (unsigned short*)(ws + 67108864);       // 67,108,864 B
    unsigned short* w1  = (unsigned short*)(ws + 134217728);      //  1,024,000 B
    unsigned short* w2  = (unsigned short*)(ws + 135241728);      //  2,048,000 B
    float* part2 = (float*)(ws + 137289728);                      //  2,097,152 B
    float* part3 = (float*)(ws + 139386880);                      //    262,144 B
    float* g1    = (float*)(ws + 139649024);                      //      2,560 B
    float* g2    = (float*)(ws + 139651584);                      //      2,560 B
    float* st1   = (float*)(ws + 139654144);                      //      1,024 B
    float* st2   = (float*)(ws + 139655168);                      //      1,024 B
    float* st3   = (float*)(ws + 139656192);                      //      1,024 B
    float* zbuf  = (float*)(ws + 139657216);                      //        256 B

    float* yout  = (float*)d_out;
    float* xskip = (float*)d_out + Y_SZ;

    gate2_kernel<<<1, 256, 0, stream>>>(t, l1_gw, l1_gb, g1, l2_gw, l2_gb, g2, zbuf);
    synth2_kernel<<<6000, 256, 0, stream>>>(g1, l1_c5, l1_c3, l1_c1, l1_a3, l1_a5, w1,
                                            g2, l2_c5, l2_c3, l2_c1, l2_a3, l2_a5, w2);
    x_to_cl<<<2048, 256, 0, stream>>>(x, xcl);

    // layer 1: conv (bf16 CL in -> bf16 CL-64 raw h2) + fused stats partials
    conv5_mfma<32, 2048, false><<<2048, 512, 0, stream>>>(xcl, w1, h2, part1, zbuf);
    stats_fin<2048><<<128, 256, 0, stream>>>(part1, st1, 1.f / SP);
    norm_mish_cl_kernel<<<16384, 256, 0, stream>>>(h2, st1, l1_ga, l1_be);

    // layer 2: conv (bf16 CL in -> bf16 grouped-8 raw h3, overwrites xcl)
    conv5_mfma<64, 2048, true><<<2048, 512, 0, stream>>>(h2, w2, h3, part2, zbuf);
    stats_fin<2048><<<128, 256, 0, stream>>>(part2, st2, 1.f / SP);

    // downsample: norm+mish(h3) -> writes f32 xskip + conv -> raw y + partials
    down_conv_kernel<<<NB * 32 * 8, 256, 0, stream>>>(h3, down_w, st2, l2_ga, l2_be,
                                                      xskip, yout, part3);
    stats_fin<256><<<128, 256, 0, stream>>>(part3, st3, 1.f / 32768.f);
    norm_mish_kernel<15><<<(NC * 32768 / 4 + 255) / 256, 256, 0, stream>>>(
        yout, st3, dn_ga, dn_be, NC * 32768 / 4);
}